// Round 13
// baseline (157.928 us; speedup 1.0000x reference)
//
#include <hip/hip_runtime.h>
#include <math.h>

// Problem constants
constexpr int BATCH  = 2;
constexpr int SEQ    = 2048;
constexpr int DMODEL = 512;
constexpr int NH     = 8;
constexpr int DHEAD  = 64;
constexpr int ROWS   = BATCH * SEQ;           // 4096
constexpr size_t SZ  = (size_t)ROWS * DMODEL; // elems of one [4096][512] f32 buffer
constexpr int NSPLIT = 4;                     // attention KV-split ways

typedef __attribute__((ext_vector_type(8)))  short bf16x8;
typedef __attribute__((ext_vector_type(4)))  float f32x4;
typedef __attribute__((ext_vector_type(16))) float f32x16;

__device__ __forceinline__ ushort f2bf(float f) {
    unsigned u = __float_as_uint(f);
    unsigned r = (u + 0x7FFFu + ((u >> 16) & 1u)) >> 16;
    return (ushort)r;
}
__device__ __forceinline__ float bf2f(ushort u) {
    return __uint_as_float((unsigned)u << 16);
}

// pack 2 f32 -> 2 bf16 (RNE) in one instruction
__device__ __forceinline__ unsigned cvtpk_bf16(float lo, float hi) {
    unsigned r;
    asm("v_cvt_pk_bf16_f32 %0, %1, %2" : "=v"(r) : "v"(lo), "v"(hi));
    return r;
}

__device__ __forceinline__ void gload_lds16(const void* g, void* l) {
    __builtin_amdgcn_global_load_lds(
        (const __attribute__((address_space(1))) void*)g,
        (__attribute__((address_space(3))) void*)l, 16, 0, 0);
}

union u32x4_bf16x8 { unsigned u[4]; bf16x8 v; };

// ---------------------------------------------------------------------------
// Mask-encoding detector, parallel. flag MUST be zeroed before launch.
// ---------------------------------------------------------------------------
__global__ __launch_bounds__(256) void detect_mask_k(
    const uint4* __restrict__ m, int* __restrict__ flag)
{
    const int i = blockIdx.x * 256 + threadIdx.x;
    const uint4 v = m[i];
    unsigned b0 = 0, b1 = 0;
    #pragma unroll
    for (int c = 0; c < 4; ++c) {
        const unsigned u = (&v.x)[c];
        b0 |= (u > 1u) ? 1u : 0u;
        b1 |= (u != 0u && u != 0x3F800000u) ? 1u : 0u;
    }
    const int lane = threadIdx.x & 63;
    if (__any(b0) && lane == 0) atomicOr(flag, 1);
    if (__any(b1) && lane == 0) atomicOr(flag, 2);
}

// ---------------------------------------------------------------------------
// Fused prep: [0,2048) x f32->bf16 conv | [2048,2816) weight transpose+conv
//             [2816, 2816+32768) mask bitmask compaction
// ---------------------------------------------------------------------------
__global__ __launch_bounds__(256) void prep_all_k(
    const float* __restrict__ x, ushort* __restrict__ xb,
    const float* __restrict__ Wq, const float* __restrict__ Wp,
    const float* __restrict__ W1w, const float* __restrict__ W2w,
    ushort* __restrict__ WqT, ushort* __restrict__ WpT,
    ushort* __restrict__ W1T, ushort* __restrict__ W2T,
    const void* __restrict__ maskp, const int* __restrict__ flagp,
    unsigned long long* __restrict__ bits)
{
    __shared__ ushort T[64][65];
    const int bid = blockIdx.x;
    const int t = threadIdx.x;

    if (bid < 2048) {           // x f32 -> bf16
        const size_t i = ((size_t)bid * 256 + t) * 4;
        float4 v = *(const float4*)(x + i);
        ushort4 o;
        o.x = f2bf(v.x); o.y = f2bf(v.y); o.z = f2bf(v.z); o.w = f2bf(v.w);
        *(ushort4*)(xb + i) = o;
        return;
    }
    if (bid >= 2816) {          // mask -> bitmask
        const int w = (bid - 2816) * 4 + (t >> 6);
        const int lane = t & 63;
        const size_t idx = ((size_t)w << 6) + lane;
        const int f = *flagp;
        bool mv;
        if (!(f & 1))      mv = ((const int*)maskp)[idx] != 0;
        else if (!(f & 2)) mv = ((const float*)maskp)[idx] != 0.f;
        else               mv = ((const unsigned char*)maskp)[idx] != 0;
        unsigned long long bal = __ballot(mv);
        if (lane == 0) bits[w] = bal;
        return;
    }
    // weight transpose+convert, 64x64 tiles
    const int wb = bid - 2048;
    const float* W; ushort* Wt; int K, N, tix, tiy;
    if (wb < 192)      { W = Wq;  Wt = WqT; K = 512;  N = 1536; tix = wb % 24;        tiy = wb / 24; }
    else if (wb < 256) { W = Wp;  Wt = WpT; K = 512;  N = 512;  tix = (wb-192) % 8;   tiy = (wb-192) / 8; }
    else if (wb < 512) { W = W1w; Wt = W1T; K = 512;  N = 2048; tix = (wb-256) % 32;  tiy = (wb-256) / 32; }
    else               { W = W2w; Wt = W2T; K = 2048; N = 512;  tix = (wb-512) % 8;   tiy = (wb-512) / 8; }
    const int k0 = tiy * 64, n0 = tix * 64;
    const int r = t >> 4, c4 = (t & 15) * 4;
    #pragma unroll
    for (int it = 0; it < 4; ++it) {
        const int row = it*16 + r;
        float4 v = *(const float4*)&W[(size_t)(k0 + row) * N + n0 + c4];
        T[c4+0][row] = f2bf(v.x);
        T[c4+1][row] = f2bf(v.y);
        T[c4+2][row] = f2bf(v.z);
        T[c4+3][row] = f2bf(v.w);
    }
    __syncthreads();
    #pragma unroll
    for (int it = 0; it < 4; ++it) {
        const int row = it*16 + r;
        ushort4 o;
        o.x = T[row][c4+0]; o.y = T[row][c4+1];
        o.z = T[row][c4+2]; o.w = T[row][c4+3];
        *(ushort4*)&Wt[(size_t)(n0 + row) * K + k0 + c4] = o;
    }
}

// ---------------------------------------------------------------------------
// bf16 MFMA GEMM: C[M,N] = A[M,K] @ Wt[N,K]^T + bias.
// DB=0: single-buffer (round-10 proven best for grid >= 3 blocks/CU).
// DB=1: 2-phase double-buffer (T3-minimal) -- ONLY for grid-limited kernels
//       (proj/MLP2 at 512 blocks = 2 blocks/CU; LDS doubling there is free).
// EPI: 1 = relu(bias) -> bf16 | 3 = QKV scatter (V transposed) | 4 = bias -> bf16
// ---------------------------------------------------------------------------
template<int EPI, int BM, int BN, int DB>
__global__ __launch_bounds__(256) void mgemm_k(
    const ushort* __restrict__ A,   // [M][K] bf16
    const ushort* __restrict__ Wt,  // [N][K] bf16
    const float* __restrict__ bias, // [N] f32
    ushort* __restrict__ Cb,
    ushort* __restrict__ Qo, ushort* __restrict__ Ko, ushort* __restrict__ Vo,
    int M, int N, int K)
{
    constexpr int WM  = BM / 2, WN = BN / 2;
    constexpr int MF  = WM / 16, NF = WN / 16;
    constexpr int APW = BM / 32;
    constexpr int BPW = BN / 32;
    constexpr int NBUF = DB ? 2 : 1;

    __shared__ ushort As[NBUF][BM * 64];
    __shared__ ushort Bs[NBUF][BN * 64];

    const int tid  = threadIdx.x;
    const int wid  = tid >> 6, lane = tid & 63;
    const int lq   = lane & 15, lg = lane >> 4;
    const int wr   = wid >> 1,  wc = wid & 1;
    const int bm   = blockIdx.y * BM, bn = blockIdx.x * BN;

    const int srow0 = lane >> 3;
    const int sch   = lane & 7;

    f32x4 acc[MF][NF] = {};

    auto STAGE = [&](int buf, int kstep) {
        const int k0 = kstep * 64;
        #pragma unroll
        for (int i = 0; i < APW; ++i) {
            const int seg = wid * APW + i;
            const int row = seg * 8 + srow0;
            const int c16 = sch ^ (row & 7);
            gload_lds16(A + (size_t)(bm + row) * K + k0 + c16 * 8, &As[buf][seg * 512]);
        }
        #pragma unroll
        for (int i = 0; i < BPW; ++i) {
            const int seg = wid * BPW + i;
            const int row = seg * 8 + srow0;
            const int c16 = sch ^ (row & 7);
            gload_lds16(Wt + (size_t)(bn + row) * K + k0 + c16 * 8, &Bs[buf][seg * 512]);
        }
    };

    auto COMPUTE = [&](int buf) {
        #pragma unroll
        for (int ks = 0; ks < 2; ++ks) {
            bf16x8 af[MF], bfr[NF];
            #pragma unroll
            for (int m = 0; m < MF; ++m) {
                const int row = wr*WM + m*16 + lq;
                const int c16 = (ks*4 + lg) ^ (row & 7);
                af[m] = *(const bf16x8*)&As[buf][row * 64 + c16 * 8];
            }
            #pragma unroll
            for (int n = 0; n < NF; ++n) {
                const int row = wc*WN + n*16 + lq;
                const int c16 = (ks*4 + lg) ^ (row & 7);
                bfr[n] = *(const bf16x8*)&Bs[buf][row * 64 + c16 * 8];
            }
            #pragma unroll
            for (int m = 0; m < MF; ++m)
                #pragma unroll
                for (int n = 0; n < NF; ++n)
                    acc[m][n] = __builtin_amdgcn_mfma_f32_16x16x32_bf16(
                        af[m], bfr[n], acc[m][n], 0, 0, 0);
        }
    };

    if (DB) {
        // 2-phase pipeline; K/64 even for our shapes (8 or 32).
        const int nk = K / 64;
        STAGE(0, 0);
        __syncthreads();
        for (int kk = 0; kk < nk; kk += 2) {
            STAGE(1, kk + 1);
            COMPUTE(0);
            __syncthreads();
            if (kk + 2 < nk) STAGE(0, kk + 2);
            COMPUTE(1);
            __syncthreads();
        }
    } else {
        for (int kk = 0; kk < K / 64; ++kk) {
            __syncthreads();
            STAGE(0, kk);
            __syncthreads();
            COMPUTE(0);
        }
    }

    #pragma unroll
    for (int m = 0; m < MF; ++m) {
        const int row0 = bm + wr*WM + m*16 + lg*4;
        #pragma unroll
        for (int n = 0; n < NF; ++n) {
            const int col = bn + wc*WN + n*16 + lq;
            const float bv = bias[col];
            float v[4];
            #pragma unroll
            for (int r = 0; r < 4; ++r) {
                v[r] = acc[m][n][r] + bv;
                if (EPI == 1) v[r] = fmaxf(v[r], 0.f);
            }
            if (EPI == 3) {
                const int part = col >> 9, hc = col & 511;
                const int hh = hc >> 6, d0 = hc & 63;
                const int bidx = row0 >> 11, nrow0 = row0 & 2047;
                if (part == 2) {
                    ushort4 pv;
                    pv.x = f2bf(v[0]); pv.y = f2bf(v[1]);
                    pv.z = f2bf(v[2]); pv.w = f2bf(v[3]);
                    *(ushort4*)(Vo + (((size_t)bidx*NH + hh)*DHEAD + d0)*SEQ + nrow0) = pv;
                } else {
                    ushort* dst = (part == 0) ? Qo : Ko;
                    #pragma unroll
                    for (int r = 0; r < 4; ++r)
                        dst[((((size_t)bidx*NH + hh)*SEQ + nrow0 + r) << 6) + d0] = f2bf(v[r]);
                }
            } else {
                #pragma unroll
                for (int r = 0; r < 4; ++r)
                    Cb[(size_t)(row0 + r) * N + col] = f2bf(v[r]);
            }
        }
    }
}

// ---------------------------------------------------------------------------
// bf16 MFMA flash attention, v7 (round-10 proven config, (256,4)).
//  - S^T = mfma_32x32x16(K, Q): softmax rows lane-local (q = lane&31)
//  - P stays in registers: cvt_pk + half-exchange (shfl_xor 32) builds PV A-frags
//  - defer-max THR=8 (exact LSE merge), k2 scale folded into Q regs
// Grid: (256, NSPLIT); x = tile*16 + bh so linear%8 = bh%8 (XCD locality).
// ---------------------------------------------------------------------------
__global__ __launch_bounds__(256, 4) void attn_mfma_k(
    const ushort* __restrict__ Qb, const ushort* __restrict__ Kb,
    const ushort* __restrict__ Vtb, const unsigned long long* __restrict__ mbits,
    ushort* __restrict__ Opart, float2* __restrict__ MLpart)
{
    __shared__ ushort Klds[2][64 * 64];   // [key][d], XOR-swizzled 16B chunks
    __shared__ ushort Vlds[2][64 * 64];   // [d][key], XOR-swizzled

    const int tid  = threadIdx.x;
    const int wid  = tid >> 6;
    const int lane = tid & 63;
    const int l31  = lane & 31;
    const int hi   = lane >> 5;

    const int bh   = blockIdx.x & 15;
    const int tile = blockIdx.x >> 4;     // 0..15 (SEQ/128 q-tiles)
    const int b    = bh >> 3;
    const int qw   = tile * 128 + wid * 32;
    const int s    = blockIdx.y;
    const int c0   = s * 8, c1 = c0 + 8;

    const float k2 = 0.125f * 1.44269504f;   // 1/sqrt(dh) * log2(e)

    // Q fragments (B-operand of 32x32x16), pre-scaled by k2.
    bf16x8 qf[4];
    {
        const ushort* Qg = Qb + ((size_t)bh * SEQ + qw + l31) * DHEAD;
        #pragma unroll
        for (int kd = 0; kd < 4; ++kd) {
            bf16x8 raw = *(const bf16x8*)(Qg + kd*16 + hi*8);
            u32x4_bf16x8 cc;
            #pragma unroll
            for (int p2 = 0; p2 < 4; ++p2) {
                const float a = bf2f((ushort)raw[2*p2])   * k2;
                const float c = bf2f((ushort)raw[2*p2+1]) * k2;
                cc.u[p2] = cvtpk_bf16(a, c);
            }
            qf[kd] = cc.v;
        }
    }

    const int srow0 = lane >> 3;
    const int sch   = lane & 7;
    const int gc8   = (sch ^ srow0) * 8;      // inverse-swizzled global col

    const ushort* kgb  = Kb  + (size_t)bh * SEQ * DHEAD
                             + (size_t)(wid*16 + srow0) * DHEAD + gc8;
    const ushort* vgb0 = Vtb + (size_t)bh * DHEAD * SEQ
                             + (size_t)(wid*16 + srow0) * SEQ + gc8;
    const ushort* vgb1 = vgb0 + 8 * SEQ;

    ushort* kd0 = &Klds[0][(wid*2)*512];
    ushort* kd1 = &Klds[1][(wid*2)*512];
    ushort* vd0 = &Vlds[0][(wid*2)*512];
    ushort* vd1 = &Vlds[1][(wid*2)*512];

    int kro0[4], kro1[4], vro[4][2];
    #pragma unroll
    for (int kd = 0; kd < 4; ++kd) {
        kro0[kd] = ( (l31)      * 64 + (((kd*2+hi) ^ (lane&7)) * 8) ) * 2;
        kro1[kd] = ( (32 + l31) * 64 + (((kd*2+hi) ^ (lane&7)) * 8) ) * 2;
    }
    #pragma unroll
    for (int ks = 0; ks < 4; ++ks)
        #pragma unroll
        for (int dt = 0; dt < 2; ++dt)
            vro[ks][dt] = ( (dt*32 + l31) * 64 + (((ks*2+hi) ^ (lane&7)) * 8) ) * 2;

    const char* kbase0 = (const char*)&Klds[0][0];
    const char* kbase1 = (const char*)&Klds[1][0];
    const char* vbase0 = (const char*)&Vlds[0][0];
    const char* vbase1 = (const char*)&Vlds[1][0];

    const unsigned long long* mrow = mbits + ((size_t)b * SEQ + qw + l31) * (SEQ / 64);

    f32x16 o0 = {}, o1 = {};
    float mrun = -1e30f, lrun = 0.f;

    {
        const ushort* kp0 = kgb  + (size_t)c0 * 4096;
        const ushort* vq0 = vgb0 + c0 * 64;
        const ushort* vq1 = vgb1 + c0 * 64;
        gload_lds16(kp0,       kd0);
        gload_lds16(kp0 + 512, kd0 + 512);
        gload_lds16(vq0, vd0);
        gload_lds16(vq1, vd0 + 512);
    }
    const ushort* kp  = kgb  + (size_t)(c0 + 1) * 4096;
    const ushort* vp0 = vgb0 + (c0 + 1) * 64;
    const ushort* vp1 = vgb1 + (c0 + 1) * 64;
    unsigned long long mw_cur = mrow[c0];
    __syncthreads();

#define ATTN_CHUNK(CC, KD, VD, KBASE, VBASE)                                   \
    {                                                                          \
        unsigned long long mw_nxt = 0;                                         \
        if ((CC) + 1 < c1) {                                                   \
            mw_nxt = mrow[(CC) + 1];                                           \
            gload_lds16(kp,       (KD));                                       \
            gload_lds16(kp + 512, (KD) + 512);                                 \
            gload_lds16(vp0, (VD));                                            \
            gload_lds16(vp1, (VD) + 512);                                      \
            kp += 4096; vp0 += 64; vp1 += 64;                                  \
        }                                                                      \
        f32x16 st0 = {}, st1 = {};                                             \
        __builtin_amdgcn_s_setprio(1);                                         \
        _Pragma("unroll")                                                      \
        for (int kd = 0; kd < 4; ++kd) {                                       \
            bf16x8 kf0 = *(const bf16x8*)((KBASE) + kro0[kd]);                 \
            bf16x8 kf1 = *(const bf16x8*)((KBASE) + kro1[kd]);                 \
            st0 = __builtin_amdgcn_mfma_f32_32x32x16_bf16(kf0, qf[kd], st0, 0, 0, 0); \
            st1 = __builtin_amdgcn_mfma_f32_32x32x16_bf16(kf1, qf[kd], st1, 0, 0, 0); \
        }                                                                      \
        __builtin_amdgcn_s_setprio(0);                                         \
        const unsigned long long mws = mw_cur >> (hi * 4);                     \
        const unsigned mlo = (unsigned)mws, mhi2 = (unsigned)(mws >> 32);      \
        _Pragma("unroll")                                                      \
        for (int r = 0; r < 16; ++r) {                                         \
            const int pos = (r & 3) + 8 * (r >> 2);                            \
            st0[r] = ((mlo  >> pos) & 1u) ? st0[r] : -1e9f;                    \
            st1[r] = ((mhi2 >> pos) & 1u) ? st1[r] : -1e9f;                    \
        }                                                                      \
        float cm0 = fmaxf(fmaxf(fmaxf(st0[0],st0[1]),fmaxf(st0[2],st0[3])),    \
                          fmaxf(fmaxf(st0[4],st0[5]),fmaxf(st0[6],st0[7])));   \
        cm0 = fmaxf(cm0, fmaxf(fmaxf(fmaxf(st0[8],st0[9]),fmaxf(st0[10],st0[11])), \
                               fmaxf(fmaxf(st0[12],st0[13]),fmaxf(st0[14],st0[15])))); \
        float cm1 = fmaxf(fmaxf(fmaxf(st1[0],st1[1]),fmaxf(st1[2],st1[3])),    \
                          fmaxf(fmaxf(st1[4],st1[5]),fmaxf(st1[6],st1[7])));   \
        cm1 = fmaxf(cm1, fmaxf(fmaxf(fmaxf(st1[8],st1[9]),fmaxf(st1[10],st1[11])), \
                               fmaxf(fmaxf(st1[12],st1[13]),fmaxf(st1[14],st1[15])))); \
        float cmax = fmaxf(cm0, cm1);                                          \
        cmax = fmaxf(cmax, __shfl_xor(cmax, 32));                              \
        if (!__all(cmax <= mrun + 8.0f)) {                                     \
            const float mnew  = fmaxf(mrun, cmax);                             \
            const float scale = exp2f(mrun - mnew);                            \
            _Pragma("unroll")                                                  \
            for (int r = 0; r < 16; ++r) {                                     \
                const float sc = __shfl(scale, (r&3) + 8*(r>>2) + 4*hi);       \
                o0[r] *= sc; o1[r] *= sc;                                      \
            }                                                                  \
            lrun *= scale;                                                     \
            mrun = mnew;                                                       \
        }                                                                      \
        float lsum = 0.f;                                                      \
        _Pragma("unroll")                                                      \
        for (int r = 0; r < 16; ++r) {                                         \
            st0[r] = exp2f(st0[r] - mrun);                                     \
            st1[r] = exp2f(st1[r] - mrun);                                     \
            lsum += st0[r] + st1[r];                                           \
        }                                                                      \
        lsum += __shfl_xor(lsum, 32);                                          \
        lrun += lsum;                                                          \
        unsigned w0[8], w1[8];                                                 \
        _Pragma("unroll")                                                      \
        for (int g = 0; g < 4; ++g) {                                          \
            w0[2*g]   = cvtpk_bf16(st0[4*g+0], st0[4*g+1]);                    \
            w0[2*g+1] = cvtpk_bf16(st0[4*g+2], st0[4*g+3]);                    \
            w1[2*g]   = cvtpk_bf16(st1[4*g+0], st1[4*g+1]);                    \
            w1[2*g+1] = cvtpk_bf16(st1[4*g+2], st1[4*g+3]);                    \
        }                                                                      \
        unsigned rcv0[4], rcv1[4];                                             \
        _Pragma("unroll")                                                      \
        for (int i = 0; i < 4; ++i) {                                          \
            const int i2 = i >> 1, wi = i & 1;                                 \
            const unsigned s0 = hi ? w0[4*i2+wi] : w0[4*i2+2+wi];              \
            const unsigned s1 = hi ? w1[4*i2+wi] : w1[4*i2+2+wi];              \
            rcv0[i] = (unsigned)__shfl_xor((int)s0, 32);                       \
            rcv1[i] = (unsigned)__shfl_xor((int)s1, 32);                       \
        }                                                                      \
        __builtin_amdgcn_s_setprio(1);                                         \
        _Pragma("unroll")                                                      \
        for (int ks = 0; ks < 4; ++ks) {                                       \
            const int i2 = ks & 1;                                             \
            u32x4_bf16x8 fw;                                                   \
            if (ks < 2) {                                                      \
                fw.u[0] = hi ? rcv0[2*i2+0] : w0[4*i2+0];                      \
                fw.u[1] = hi ? rcv0[2*i2+1] : w0[4*i2+1];                      \
                fw.u[2] = hi ? w0[4*i2+2]   : rcv0[2*i2+0];                    \
                fw.u[3] = hi ? w0[4*i2+3]   : rcv0[2*i2+1];                    \
            } else {                                                           \
                fw.u[0] = hi ? rcv1[2*i2+0] : w1[4*i2+0];                      \
                fw.u[1] = hi ? rcv1[2*i2+1] : w1[4*i2+1];                      \
                fw.u[2] = hi ? w1[4*i2+2]   : rcv1[2*i2+0];                    \
                fw.u[3] = hi ? w1[4*i2+3]   : rcv1[2*i2+1];                    \
            }                                                                  \
            bf16x8 vf0 = *(const bf16x8*)((VBASE) + vro[ks][0]);               \
            bf16x8 vf1 = *(const bf16x8*)((VBASE) + vro[ks][1]);               \
            o0 = __builtin_amdgcn_mfma_f32_32x32x16_bf16(fw.v, vf0, o0, 0, 0, 0); \
            o1 = __builtin_amdgcn_mfma_f32_32x32x16_bf16(fw.v, vf1, o1, 0, 0, 0); \
        }                                                                      \
        __builtin_amdgcn_s_setprio(0);                                         \
        __syncthreads();                                                       \
        mw_cur = mw_nxt;                                                       \
    }

    for (int c = c0; c < c1; c += 2) {
        ATTN_CHUNK(c,     kd1, vd1, kbase0, vbase0);
        ATTN_CHUNK(c + 1, kd0, vd0, kbase1, vbase1);
    }
#undef ATTN_CHUNK

    #pragma unroll
    for (int r = 0; r < 16; ++r) {
        const int qrow = qw + (r&3) + 8*(r>>2) + 4*hi;
        const size_t base = (((size_t)s*16 + bh)*SEQ + qrow)*64;
        Opart[base + l31]      = f2bf(o0[r]);
        Opart[base + 32 + l31] = f2bf(o1[r]);
    }
    if (hi == 0) {
        float2 ml; ml.x = mrun; ml.y = lrun;
        MLpart[((size_t)s*16 + bh)*SEQ + qw + l31] = ml;
    }
}

// ---------------------------------------------------------------------------
// Combine the NSPLIT KV-split parts (exact log-sum-exp merge, base-2 domain).
// ---------------------------------------------------------------------------
__global__ __launch_bounds__(256) void attn_combine_k(
    const ushort* __restrict__ Op, const float2* __restrict__ ML,
    ushort* __restrict__ attnb)
{
    const int row  = blockIdx.x * 4 + (threadIdx.x >> 6);  // bh*SEQ + q
    const int lane = threadIdx.x & 63;
    const int bh = row >> 11, q = row & 2047;
    const int b = bh >> 3, h = bh & 7;
    float2 ml[NSPLIT];
    float m = -1e30f;
    #pragma unroll
    for (int s = 0; s < NSPLIT; ++s) {
        ml[s] = ML[(size_t)s*16*SEQ + row];
        m = fmaxf(m, ml[s].x);
    }
    float l = 0.f, o = 0.f;
    #pragma unroll
    for (int s = 0; s < NSPLIT; ++s) {
        const float a = exp2f(ml[s].x - m);
        l += ml[s].y * a;
        o += bf2f(Op[((size_t)s*16*SEQ + row)*64 + lane]) * a;
    }
    attnb[((size_t)(b*SEQ + q))*DMODEL + h*DHEAD + lane] = f2bf(o / l);
}

// ---------------------------------------------------------------------------
// out = LayerNorm(X + A)*g + b over DMODEL=512, WAVE-PER-ROW (4 rows/block).
// Lane l owns elements l*8..l*8+7; reduction = 6-step shfl_xor butterfly.
// XBF/ABF: input dtypes (0 = f32, 1 = bf16). Outputs: f32 (outf) and/or bf16.
// Grid: ROWS/4 blocks of 256.
// ---------------------------------------------------------------------------
template<int XBF, int ABF>
__global__ __launch_bounds__(256) void add_ln_k(
    const void* __restrict__ X, const void* __restrict__ Aa,
    const float* __restrict__ gg, const float* __restrict__ bb,
    float* __restrict__ outf, ushort* __restrict__ outb)
{
    const int w = threadIdx.x >> 6, l = threadIdx.x & 63;
    const int r = blockIdx.x * 4 + w;
    const size_t base = (size_t)r * DMODEL + l * 8;

    float v[8];
    if (XBF) {
        bf16x8 u = *(const bf16x8*)((const ushort*)X + base);
        #pragma unroll
        for (int j = 0; j < 8; ++j) v[j] = bf2f((ushort)u[j]);
    } else {
        float4 f0 = *(const float4*)((const float*)X + base);
        float4 f1 = *(const float4*)((const float*)X + base + 4);
        v[0]=f0.x; v[1]=f0.y; v[2]=f0.z; v[3]=f0.w;
        v[4]=f1.x; v[5]=f1.y; v[6]=f1.z; v[7]=f1.w;
    }
    if (ABF) {
        bf16x8 u = *(const bf16x8*)((const ushort*)Aa + base);
        #pragma unroll
        for (int j = 0; j < 8; ++j) v[j] += bf2f((ushort)u[j]);
    } else {
        float4 f0 = *(const float4*)((const float*)Aa + base);
        float4 f1 = *(const float4*)((const float*)Aa + base + 4);
        v[0]+=f0.x; v[1]+=f0.y; v[2]+=f0.z; v[3]+=f0.w;
        v[4]+=f1.x; v[5]+=f1.y; v[6]+=f1.z; v[7]+=f1.w;
    }

    float s = 0.f, ss = 0.f;
    #pragma unroll
    for (int j = 0; j < 8; ++j) { s += v[j]; ss += v[j]*v[j]; }
    #pragma unroll
    for (int off = 32; off > 0; off >>= 1) {
        s  += __shfl_xor(s,  off);
        ss += __shfl_xor(ss, off);
    }
    const float mean = s * (1.0f / DMODEL);
    const float var  = ss * (1.0f / DMODEL) - mean * mean;
    const float rstd = rsqrtf(var + 1e-5f);

    const float4 g0 = *(const float4*)(gg + l*8);
    const float4 g1 = *(const float4*)(gg + l*8 + 4);
    const float4 b0 = *(const float4*)(bb + l*8);
    const float4 b1 = *(const float4*)(bb + l*8 + 4);
    float o[8];
    o[0] = (v[0]-mean)*rstd*g0.x + b0.x;
    o[1] = (v[1]-mean)*rstd*g0.y + b0.y;
    o[2] = (v[2]-mean)*rstd*g0.z + b0.z;
    o[3] = (v[3]-mean)*rstd*g0.w + b0.w;
    o[4] = (v[4]-mean)*rstd*g1.x + b1.x;
    o[5] = (v[5]-mean)*rstd*g1.y + b1.y;
    o[6] = (v[6]-mean)*rstd*g1.z + b1.z;
    o[7] = (v[7]-mean)*rstd*g1.w + b1.w;

    if (outf) {
        float4 f0, f1;
        f0.x=o[0]; f0.y=o[1]; f0.z=o[2]; f0.w=o[3];
        f1.x=o[4]; f1.y=o[5]; f1.z=o[6]; f1.w=o[7];
        *(float4*)(outf + base)     = f0;
        *(float4*)(outf + base + 4) = f1;
    }
    if (outb) {
        u32x4_bf16x8 cc;
        cc.u[0] = cvtpk_bf16(o[0], o[1]);
        cc.u[1] = cvtpk_bf16(o[2], o[3]);
        cc.u[2] = cvtpk_bf16(o[4], o[5]);
        cc.u[3] = cvtpk_bf16(o[6], o[7]);
        *(bf16x8*)(outb + base) = cc.v;
    }
}

// ---------------------------------------------------------------------------
extern "C" void kernel_launch(void* const* d_in, const int* in_sizes, int n_in,
                              void* d_out, int out_size, void* d_ws, size_t ws_size,
                              hipStream_t stream)
{
    const float* x      = (const float*)d_in[0];
    const void*  mask   = d_in[1];
    const float* W_qkv  = (const float*)d_in[2];
    const float* b_qkv  = (const float*)d_in[3];
    const float* W_proj = (const float*)d_in[4];
    const float* b_proj = (const float*)d_in[5];
    const float* ln1_g  = (const float*)d_in[6];
    const float* ln1_b  = (const float*)d_in[7];
    const float* W1     = (const float*)d_in[8];
    const float* b1     = (const float*)d_in[9];
    const float* W2     = (const float*)d_in[10];
    const float* b2     = (const float*)d_in[11];
    const float* ln2_g  = (const float*)d_in[12];
    const float* ln2_b  = (const float*)d_in[13];

    float* ws = (float*)d_ws;
    ushort* xb    = (ushort*)ws;
    ushort* Qb    = (ushort*)(ws + SZ/2);
    ushort* Kb    = (ushort*)(ws + SZ);
    ushort* Vtb   = (ushort*)(ws + SZ + SZ/2);   // [B,H,DHEAD,SEQ]
    ushort* attnb = (ushort*)(ws + 2*SZ);
    ushort* Opart = (ushort*)(ws + 2*SZ + SZ/2); // [4][16][SEQ][64] bf16
    float2* MLp   = (float2*)(ws + 4*SZ + SZ/2); // [4][16][SEQ]
    ushort* ap    = (ushort*)(ws + 2*SZ + SZ/2); // bf16, overlays Opart (dead)
    ushort* x1b   = (ushort*)(ws + 3*SZ);        // bf16
    ushort* mbuf  = (ushort*)(ws + 3*SZ + SZ/2); // bf16
    ushort* hb    = (ushort*)ws;
    ushort* WqkvT = (ushort*)(ws + 5*SZ);                    // 512*1536
    ushort* WprojT= (ushort*)(ws + 5*SZ + 393216);           // 512*512
    ushort* W1T   = (ushort*)(ws + 5*SZ + 524288);           // 2048*512
    ushort* W2T   = (ushort*)(ws + 5*SZ + 1048576);          // 512*2048
    unsigned long long* bits = (unsigned long long*)(ws + 5*SZ + 1572864);
    int*    flag  = (int*)(ws + 5*SZ + 1572864 + 262144);

    float* out = (float*)d_out;

    hipMemsetAsync(flag, 0, 4, stream);
    detect_mask_k<<<64, 256, 0, stream>>>((const uint4*)mask, flag);
    prep_all_k<<<2816 + 32768, 256, 0, stream>>>(
        x, xb, W_qkv, W_proj, W1, W2, WqkvT, WprojT, W1T, W2T,
        mask, flag, bits);

    // QKV: [4096,512]@[512,1536] -> bf16 Q/K (row) + V (transposed)
    mgemm_k<3,64,128,0><<<dim3(12, 64), 256, 0, stream>>>(xb, WqkvT, b_qkv,
        nullptr, Qb, Kb, Vtb, ROWS, 3*DMODEL, DMODEL);
    // attention partials (4-way KV split) -> combine -> attnb bf16
    attn_mfma_k<<<dim3(256, NSPLIT), 256, 0, stream>>>(
        Qb, Kb, Vtb, bits, Opart, MLp);
    attn_combine_k<<<BATCH*NH*SEQ/4, 256, 0, stream>>>(Opart, MLp, attnb);
    // proj: [4096,512]@[512,512] -> ap bf16  (grid-limited -> 2-phase pipeline)
    mgemm_k<4,64,64,1><<<dim3(8, 64), 256, 0, stream>>>(attnb, WprojT, b_proj,
        ap, nullptr, nullptr, nullptr, ROWS, DMODEL, DMODEL);
    // x1b = LN(xb + ap)
    add_ln_k<1,1><<<ROWS/4, 256, 0, stream>>>(xb, ap, ln1_g, ln1_b, nullptr, x1b);
    // MLP1: relu([4096,512]@[512,2048]) -> bf16 hb
    mgemm_k<1,64,128,0><<<dim3(16, 64), 256, 0, stream>>>(x1b, W1T, b1,
        hb, nullptr, nullptr, nullptr, ROWS, 2048, DMODEL);
    // MLP2: relu([4096,2048]@[2048,512]) -> bf16 mbuf (grid-limited -> 2-phase)
    mgemm_k<1,64,64,1><<<dim3(8, 64), 256, 0, stream>>>(hb, W2T, b2,
        mbuf, nullptr, nullptr, nullptr, ROWS, DMODEL, 2048);
    // out = LN(x1b + mbuf) -> f32 d_out
    add_ln_k<1,1><<<ROWS/4, 256, 0, stream>>>(x1b, mbuf, ln2_g, ln2_b, out, nullptr);
}

// Round 14
// 148.971 us; speedup vs baseline: 1.0601x; 1.0601x over previous
//
#include <hip/hip_runtime.h>
#include <math.h>

// Problem constants
constexpr int BATCH  = 2;
constexpr int SEQ    = 2048;
constexpr int DMODEL = 512;
constexpr int NH     = 8;
constexpr int DHEAD  = 64;
constexpr int ROWS   = BATCH * SEQ;           // 4096
constexpr size_t SZ  = (size_t)ROWS * DMODEL; // elems of one [4096][512] f32 buffer
constexpr int NSPLIT = 4;                     // attention KV-split ways

typedef __attribute__((ext_vector_type(8)))  short bf16x8;
typedef __attribute__((ext_vector_type(4)))  float f32x4;
typedef __attribute__((ext_vector_type(16))) float f32x16;

__device__ __forceinline__ ushort f2bf(float f) {
    unsigned u = __float_as_uint(f);
    unsigned r = (u + 0x7FFFu + ((u >> 16) & 1u)) >> 16;
    return (ushort)r;
}
__device__ __forceinline__ float bf2f(ushort u) {
    return __uint_as_float((unsigned)u << 16);
}

// pack 2 f32 -> 2 bf16 (RNE) in one instruction
__device__ __forceinline__ unsigned cvtpk_bf16(float lo, float hi) {
    unsigned r;
    asm("v_cvt_pk_bf16_f32 %0, %1, %2" : "=v"(r) : "v"(lo), "v"(hi));
    return r;
}

__device__ __forceinline__ void gload_lds16(const void* g, void* l) {
    __builtin_amdgcn_global_load_lds(
        (const __attribute__((address_space(1))) void*)g,
        (__attribute__((address_space(3))) void*)l, 16, 0, 0);
}

union u32x4_bf16x8 { unsigned u[4]; bf16x8 v; };

// ---------------------------------------------------------------------------
// Mask-encoding detector, parallel. flag MUST be zeroed before launch.
// ---------------------------------------------------------------------------
__global__ __launch_bounds__(256) void detect_mask_k(
    const uint4* __restrict__ m, int* __restrict__ flag)
{
    const int i = blockIdx.x * 256 + threadIdx.x;
    const uint4 v = m[i];
    unsigned b0 = 0, b1 = 0;
    #pragma unroll
    for (int c = 0; c < 4; ++c) {
        const unsigned u = (&v.x)[c];
        b0 |= (u > 1u) ? 1u : 0u;
        b1 |= (u != 0u && u != 0x3F800000u) ? 1u : 0u;
    }
    const int lane = threadIdx.x & 63;
    if (__any(b0) && lane == 0) atomicOr(flag, 1);
    if (__any(b1) && lane == 0) atomicOr(flag, 2);
}

// ---------------------------------------------------------------------------
// Fused prep: [0,2048) x f32->bf16 conv | [2048,2816) weight transpose+conv
//             [2816, 2816+32768) mask bitmask compaction
// ---------------------------------------------------------------------------
__global__ __launch_bounds__(256) void prep_all_k(
    const float* __restrict__ x, ushort* __restrict__ xb,
    const float* __restrict__ Wq, const float* __restrict__ Wp,
    const float* __restrict__ W1w, const float* __restrict__ W2w,
    ushort* __restrict__ WqT, ushort* __restrict__ WpT,
    ushort* __restrict__ W1T, ushort* __restrict__ W2T,
    const void* __restrict__ maskp, const int* __restrict__ flagp,
    unsigned long long* __restrict__ bits)
{
    __shared__ ushort T[64][65];
    const int bid = blockIdx.x;
    const int t = threadIdx.x;

    if (bid < 2048) {           // x f32 -> bf16
        const size_t i = ((size_t)bid * 256 + t) * 4;
        float4 v = *(const float4*)(x + i);
        ushort4 o;
        o.x = f2bf(v.x); o.y = f2bf(v.y); o.z = f2bf(v.z); o.w = f2bf(v.w);
        *(ushort4*)(xb + i) = o;
        return;
    }
    if (bid >= 2816) {          // mask -> bitmask
        const int w = (bid - 2816) * 4 + (t >> 6);
        const int lane = t & 63;
        const size_t idx = ((size_t)w << 6) + lane;
        const int f = *flagp;
        bool mv;
        if (!(f & 1))      mv = ((const int*)maskp)[idx] != 0;
        else if (!(f & 2)) mv = ((const float*)maskp)[idx] != 0.f;
        else               mv = ((const unsigned char*)maskp)[idx] != 0;
        unsigned long long bal = __ballot(mv);
        if (lane == 0) bits[w] = bal;
        return;
    }
    // weight transpose+convert, 64x64 tiles
    const int wb = bid - 2048;
    const float* W; ushort* Wt; int K, N, tix, tiy;
    if (wb < 192)      { W = Wq;  Wt = WqT; K = 512;  N = 1536; tix = wb % 24;        tiy = wb / 24; }
    else if (wb < 256) { W = Wp;  Wt = WpT; K = 512;  N = 512;  tix = (wb-192) % 8;   tiy = (wb-192) / 8; }
    else if (wb < 512) { W = W1w; Wt = W1T; K = 512;  N = 2048; tix = (wb-256) % 32;  tiy = (wb-256) / 32; }
    else               { W = W2w; Wt = W2T; K = 2048; N = 512;  tix = (wb-512) % 8;   tiy = (wb-512) / 8; }
    const int k0 = tiy * 64, n0 = tix * 64;
    const int r = t >> 4, c4 = (t & 15) * 4;
    #pragma unroll
    for (int it = 0; it < 4; ++it) {
        const int row = it*16 + r;
        float4 v = *(const float4*)&W[(size_t)(k0 + row) * N + n0 + c4];
        T[c4+0][row] = f2bf(v.x);
        T[c4+1][row] = f2bf(v.y);
        T[c4+2][row] = f2bf(v.z);
        T[c4+3][row] = f2bf(v.w);
    }
    __syncthreads();
    #pragma unroll
    for (int it = 0; it < 4; ++it) {
        const int row = it*16 + r;
        ushort4 o;
        o.x = T[row][c4+0]; o.y = T[row][c4+1];
        o.z = T[row][c4+2]; o.w = T[row][c4+3];
        *(ushort4*)&Wt[(size_t)(n0 + row) * K + k0 + c4] = o;
    }
}

// ---------------------------------------------------------------------------
// bf16 MFMA GEMM (m97 structure, single-buffered — round-10 proven config)
// + T1 XCD-aware bijective block swizzle: each XCD gets a contiguous chunk of
//   the linearized grid, so its A-slice (+ shared W panels) stay L2-resident.
//   Requires total blocks % 8 == 0 (true: 768/512/1024/512).
// EPI: 1 = relu(bias) -> bf16 | 3 = QKV scatter (V transposed) | 4 = bias -> bf16
// ---------------------------------------------------------------------------
template<int EPI, int BM, int BN>
__global__ __launch_bounds__(256) void mgemm_k(
    const ushort* __restrict__ A,   // [M][K] bf16
    const ushort* __restrict__ Wt,  // [N][K] bf16
    const float* __restrict__ bias, // [N] f32
    ushort* __restrict__ Cb,
    ushort* __restrict__ Qo, ushort* __restrict__ Ko, ushort* __restrict__ Vo,
    int M, int N, int K)
{
    constexpr int WM  = BM / 2, WN = BN / 2;
    constexpr int MF  = WM / 16, NF = WN / 16;
    constexpr int APW = BM / 32;
    constexpr int BPW = BN / 32;

    __shared__ ushort As[BM * 64];
    __shared__ ushort Bs[BN * 64];

    const int tid  = threadIdx.x;
    const int wid  = tid >> 6, lane = tid & 63;
    const int lq   = lane & 15, lg = lane >> 4;
    const int wr   = wid >> 1,  wc = wid & 1;

    // XCD-aware bijective swizzle (nwg % 8 == 0): linear dispatch order is
    // round-robin over XCDs; give XCD k the contiguous chunk [k*nwg/8, ...).
    const int gx   = gridDim.x;
    const int nwg  = gx * gridDim.y;
    const int lin  = blockIdx.y * gx + blockIdx.x;
    const int cpx  = nwg >> 3;                    // chunk per XCD
    const int pos  = (lin & 7) * cpx + (lin >> 3);
    const int bm   = (pos / gx) * BM, bn = (pos % gx) * BN;

    const int srow0 = lane >> 3;
    const int sch   = lane & 7;

    f32x4 acc[MF][NF] = {};

    for (int k0 = 0; k0 < K; k0 += 64) {
        __syncthreads();
        #pragma unroll
        for (int i = 0; i < APW; ++i) {
            const int seg = wid * APW + i;
            const int row = seg * 8 + srow0;
            const int c16 = sch ^ (row & 7);
            gload_lds16(A + (size_t)(bm + row) * K + k0 + c16 * 8, As + seg * 512);
        }
        #pragma unroll
        for (int i = 0; i < BPW; ++i) {
            const int seg = wid * BPW + i;
            const int row = seg * 8 + srow0;
            const int c16 = sch ^ (row & 7);
            gload_lds16(Wt + (size_t)(bn + row) * K + k0 + c16 * 8, Bs + seg * 512);
        }
        __syncthreads();

        #pragma unroll
        for (int ks = 0; ks < 2; ++ks) {
            bf16x8 af[MF], bfr[NF];
            #pragma unroll
            for (int m = 0; m < MF; ++m) {
                const int row = wr*WM + m*16 + lq;
                const int c16 = (ks*4 + lg) ^ (row & 7);
                af[m] = *(const bf16x8*)&As[row * 64 + c16 * 8];
            }
            #pragma unroll
            for (int n = 0; n < NF; ++n) {
                const int row = wc*WN + n*16 + lq;
                const int c16 = (ks*4 + lg) ^ (row & 7);
                bfr[n] = *(const bf16x8*)&Bs[row * 64 + c16 * 8];
            }
            #pragma unroll
            for (int m = 0; m < MF; ++m)
                #pragma unroll
                for (int n = 0; n < NF; ++n)
                    acc[m][n] = __builtin_amdgcn_mfma_f32_16x16x32_bf16(
                        af[m], bfr[n], acc[m][n], 0, 0, 0);
        }
    }

    #pragma unroll
    for (int m = 0; m < MF; ++m) {
        const int row0 = bm + wr*WM + m*16 + lg*4;
        #pragma unroll
        for (int n = 0; n < NF; ++n) {
            const int col = bn + wc*WN + n*16 + lq;
            const float bv = bias[col];
            float v[4];
            #pragma unroll
            for (int r = 0; r < 4; ++r) {
                v[r] = acc[m][n][r] + bv;
                if (EPI == 1) v[r] = fmaxf(v[r], 0.f);
            }
            if (EPI == 3) {
                const int part = col >> 9, hc = col & 511;
                const int hh = hc >> 6, d0 = hc & 63;
                const int bidx = row0 >> 11, nrow0 = row0 & 2047;
                if (part == 2) {
                    ushort4 pv;
                    pv.x = f2bf(v[0]); pv.y = f2bf(v[1]);
                    pv.z = f2bf(v[2]); pv.w = f2bf(v[3]);
                    *(ushort4*)(Vo + (((size_t)bidx*NH + hh)*DHEAD + d0)*SEQ + nrow0) = pv;
                } else {
                    ushort* dst = (part == 0) ? Qo : Ko;
                    #pragma unroll
                    for (int r = 0; r < 4; ++r)
                        dst[((((size_t)bidx*NH + hh)*SEQ + nrow0 + r) << 6) + d0] = f2bf(v[r]);
                }
            } else {
                #pragma unroll
                for (int r = 0; r < 4; ++r)
                    Cb[(size_t)(row0 + r) * N + col] = f2bf(v[r]);
            }
        }
    }
}

// ---------------------------------------------------------------------------
// bf16 MFMA flash attention, v7 (round-10 proven config, (256,4)).
//  - S^T = mfma_32x32x16(K, Q): softmax rows lane-local (q = lane&31)
//  - P stays in registers: cvt_pk + half-exchange (shfl_xor 32) builds PV A-frags
//  - defer-max THR=8 (exact LSE merge), k2 scale folded into Q regs
// Grid: (256, NSPLIT); x = tile*16 + bh so linear%8 = bh%8 (XCD locality).
// ---------------------------------------------------------------------------
__global__ __launch_bounds__(256, 4) void attn_mfma_k(
    const ushort* __restrict__ Qb, const ushort* __restrict__ Kb,
    const ushort* __restrict__ Vtb, const unsigned long long* __restrict__ mbits,
    ushort* __restrict__ Opart, float2* __restrict__ MLpart)
{
    __shared__ ushort Klds[2][64 * 64];   // [key][d], XOR-swizzled 16B chunks
    __shared__ ushort Vlds[2][64 * 64];   // [d][key], XOR-swizzled

    const int tid  = threadIdx.x;
    const int wid  = tid >> 6;
    const int lane = tid & 63;
    const int l31  = lane & 31;
    const int hi   = lane >> 5;

    const int bh   = blockIdx.x & 15;
    const int tile = blockIdx.x >> 4;     // 0..15 (SEQ/128 q-tiles)
    const int b    = bh >> 3;
    const int qw   = tile * 128 + wid * 32;
    const int s    = blockIdx.y;
    const int c0   = s * 8, c1 = c0 + 8;

    const float k2 = 0.125f * 1.44269504f;   // 1/sqrt(dh) * log2(e)

    // Q fragments (B-operand of 32x32x16), pre-scaled by k2.
    bf16x8 qf[4];
    {
        const ushort* Qg = Qb + ((size_t)bh * SEQ + qw + l31) * DHEAD;
        #pragma unroll
        for (int kd = 0; kd < 4; ++kd) {
            bf16x8 raw = *(const bf16x8*)(Qg + kd*16 + hi*8);
            u32x4_bf16x8 cc;
            #pragma unroll
            for (int p2 = 0; p2 < 4; ++p2) {
                const float a = bf2f((ushort)raw[2*p2])   * k2;
                const float c = bf2f((ushort)raw[2*p2+1]) * k2;
                cc.u[p2] = cvtpk_bf16(a, c);
            }
            qf[kd] = cc.v;
        }
    }

    const int srow0 = lane >> 3;
    const int sch   = lane & 7;
    const int gc8   = (sch ^ srow0) * 8;      // inverse-swizzled global col

    const ushort* kgb  = Kb  + (size_t)bh * SEQ * DHEAD
                             + (size_t)(wid*16 + srow0) * DHEAD + gc8;
    const ushort* vgb0 = Vtb + (size_t)bh * DHEAD * SEQ
                             + (size_t)(wid*16 + srow0) * SEQ + gc8;
    const ushort* vgb1 = vgb0 + 8 * SEQ;

    ushort* kd0 = &Klds[0][(wid*2)*512];
    ushort* kd1 = &Klds[1][(wid*2)*512];
    ushort* vd0 = &Vlds[0][(wid*2)*512];
    ushort* vd1 = &Vlds[1][(wid*2)*512];

    int kro0[4], kro1[4], vro[4][2];
    #pragma unroll
    for (int kd = 0; kd < 4; ++kd) {
        kro0[kd] = ( (l31)      * 64 + (((kd*2+hi) ^ (lane&7)) * 8) ) * 2;
        kro1[kd] = ( (32 + l31) * 64 + (((kd*2+hi) ^ (lane&7)) * 8) ) * 2;
    }
    #pragma unroll
    for (int ks = 0; ks < 4; ++ks)
        #pragma unroll
        for (int dt = 0; dt < 2; ++dt)
            vro[ks][dt] = ( (dt*32 + l31) * 64 + (((ks*2+hi) ^ (lane&7)) * 8) ) * 2;

    const char* kbase0 = (const char*)&Klds[0][0];
    const char* kbase1 = (const char*)&Klds[1][0];
    const char* vbase0 = (const char*)&Vlds[0][0];
    const char* vbase1 = (const char*)&Vlds[1][0];

    const unsigned long long* mrow = mbits + ((size_t)b * SEQ + qw + l31) * (SEQ / 64);

    f32x16 o0 = {}, o1 = {};
    float mrun = -1e30f, lrun = 0.f;

    {
        const ushort* kp0 = kgb  + (size_t)c0 * 4096;
        const ushort* vq0 = vgb0 + c0 * 64;
        const ushort* vq1 = vgb1 + c0 * 64;
        gload_lds16(kp0,       kd0);
        gload_lds16(kp0 + 512, kd0 + 512);
        gload_lds16(vq0, vd0);
        gload_lds16(vq1, vd0 + 512);
    }
    const ushort* kp  = kgb  + (size_t)(c0 + 1) * 4096;
    const ushort* vp0 = vgb0 + (c0 + 1) * 64;
    const ushort* vp1 = vgb1 + (c0 + 1) * 64;
    unsigned long long mw_cur = mrow[c0];
    __syncthreads();

#define ATTN_CHUNK(CC, KD, VD, KBASE, VBASE)                                   \
    {                                                                          \
        unsigned long long mw_nxt = 0;                                         \
        if ((CC) + 1 < c1) {                                                   \
            mw_nxt = mrow[(CC) + 1];                                           \
            gload_lds16(kp,       (KD));                                       \
            gload_lds16(kp + 512, (KD) + 512);                                 \
            gload_lds16(vp0, (VD));                                            \
            gload_lds16(vp1, (VD) + 512);                                      \
            kp += 4096; vp0 += 64; vp1 += 64;                                  \
        }                                                                      \
        f32x16 st0 = {}, st1 = {};                                             \
        __builtin_amdgcn_s_setprio(1);                                         \
        _Pragma("unroll")                                                      \
        for (int kd = 0; kd < 4; ++kd) {                                       \
            bf16x8 kf0 = *(const bf16x8*)((KBASE) + kro0[kd]);                 \
            bf16x8 kf1 = *(const bf16x8*)((KBASE) + kro1[kd]);                 \
            st0 = __builtin_amdgcn_mfma_f32_32x32x16_bf16(kf0, qf[kd], st0, 0, 0, 0); \
            st1 = __builtin_amdgcn_mfma_f32_32x32x16_bf16(kf1, qf[kd], st1, 0, 0, 0); \
        }                                                                      \
        __builtin_amdgcn_s_setprio(0);                                         \
        const unsigned long long mws = mw_cur >> (hi * 4);                     \
        const unsigned mlo = (unsigned)mws, mhi2 = (unsigned)(mws >> 32);      \
        _Pragma("unroll")                                                      \
        for (int r = 0; r < 16; ++r) {                                         \
            const int pos = (r & 3) + 8 * (r >> 2);                            \
            st0[r] = ((mlo  >> pos) & 1u) ? st0[r] : -1e9f;                    \
            st1[r] = ((mhi2 >> pos) & 1u) ? st1[r] : -1e9f;                    \
        }                                                                      \
        float cm0 = fmaxf(fmaxf(fmaxf(st0[0],st0[1]),fmaxf(st0[2],st0[3])),    \
                          fmaxf(fmaxf(st0[4],st0[5]),fmaxf(st0[6],st0[7])));   \
        cm0 = fmaxf(cm0, fmaxf(fmaxf(fmaxf(st0[8],st0[9]),fmaxf(st0[10],st0[11])), \
                               fmaxf(fmaxf(st0[12],st0[13]),fmaxf(st0[14],st0[15])))); \
        float cm1 = fmaxf(fmaxf(fmaxf(st1[0],st1[1]),fmaxf(st1[2],st1[3])),    \
                          fmaxf(fmaxf(st1[4],st1[5]),fmaxf(st1[6],st1[7])));   \
        cm1 = fmaxf(cm1, fmaxf(fmaxf(fmaxf(st1[8],st1[9]),fmaxf(st1[10],st1[11])), \
                               fmaxf(fmaxf(st1[12],st1[13]),fmaxf(st1[14],st1[15])))); \
        float cmax = fmaxf(cm0, cm1);                                          \
        cmax = fmaxf(cmax, __shfl_xor(cmax, 32));                              \
        if (!__all(cmax <= mrun + 8.0f)) {                                     \
            const float mnew  = fmaxf(mrun, cmax);                             \
            const float scale = exp2f(mrun - mnew);                            \
            _Pragma("unroll")                                                  \
            for (int r = 0; r < 16; ++r) {                                     \
                const float sc = __shfl(scale, (r&3) + 8*(r>>2) + 4*hi);       \
                o0[r] *= sc; o1[r] *= sc;                                      \
            }                                                                  \
            lrun *= scale;                                                     \
            mrun = mnew;                                                       \
        }                                                                      \
        float lsum = 0.f;                                                      \
        _Pragma("unroll")                                                      \
        for (int r = 0; r < 16; ++r) {                                         \
            st0[r] = exp2f(st0[r] - mrun);                                     \
            st1[r] = exp2f(st1[r] - mrun);                                     \
            lsum += st0[r] + st1[r];                                           \
        }                                                                      \
        lsum += __shfl_xor(lsum, 32);                                          \
        lrun += lsum;                                                          \
        unsigned w0[8], w1[8];                                                 \
        _Pragma("unroll")                                                      \
        for (int g = 0; g < 4; ++g) {                                          \
            w0[2*g]   = cvtpk_bf16(st0[4*g+0], st0[4*g+1]);                    \
            w0[2*g+1] = cvtpk_bf16(st0[4*g+2], st0[4*g+3]);                    \
            w1[2*g]   = cvtpk_bf16(st1[4*g+0], st1[4*g+1]);                    \
            w1[2*g+1] = cvtpk_bf16(st1[4*g+2], st1[4*g+3]);                    \
        }                                                                      \
        unsigned rcv0[4], rcv1[4];                                             \
        _Pragma("unroll")                                                      \
        for (int i = 0; i < 4; ++i) {                                          \
            const int i2 = i >> 1, wi = i & 1;                                 \
            const unsigned s0 = hi ? w0[4*i2+wi] : w0[4*i2+2+wi];              \
            const unsigned s1 = hi ? w1[4*i2+wi] : w1[4*i2+2+wi];              \
            rcv0[i] = (unsigned)__shfl_xor((int)s0, 32);                       \
            rcv1[i] = (unsigned)__shfl_xor((int)s1, 32);                       \
        }                                                                      \
        __builtin_amdgcn_s_setprio(1);                                         \
        _Pragma("unroll")                                                      \
        for (int ks = 0; ks < 4; ++ks) {                                       \
            const int i2 = ks & 1;                                             \
            u32x4_bf16x8 fw;                                                   \
            if (ks < 2) {                                                      \
                fw.u[0] = hi ? rcv0[2*i2+0] : w0[4*i2+0];                      \
                fw.u[1] = hi ? rcv0[2*i2+1] : w0[4*i2+1];                      \
                fw.u[2] = hi ? w0[4*i2+2]   : rcv0[2*i2+0];                    \
                fw.u[3] = hi ? w0[4*i2+3]   : rcv0[2*i2+1];                    \
            } else {                                                           \
                fw.u[0] = hi ? rcv1[2*i2+0] : w1[4*i2+0];                      \
                fw.u[1] = hi ? rcv1[2*i2+1] : w1[4*i2+1];                      \
                fw.u[2] = hi ? w1[4*i2+2]   : rcv1[2*i2+0];                    \
                fw.u[3] = hi ? w1[4*i2+3]   : rcv1[2*i2+1];                    \
            }                                                                  \
            bf16x8 vf0 = *(const bf16x8*)((VBASE) + vro[ks][0]);               \
            bf16x8 vf1 = *(const bf16x8*)((VBASE) + vro[ks][1]);               \
            o0 = __builtin_amdgcn_mfma_f32_32x32x16_bf16(fw.v, vf0, o0, 0, 0, 0); \
            o1 = __builtin_amdgcn_mfma_f32_32x32x16_bf16(fw.v, vf1, o1, 0, 0, 0); \
        }                                                                      \
        __builtin_amdgcn_s_setprio(0);                                         \
        __syncthreads();                                                       \
        mw_cur = mw_nxt;                                                       \
    }

    for (int c = c0; c < c1; c += 2) {
        ATTN_CHUNK(c,     kd1, vd1, kbase0, vbase0);
        ATTN_CHUNK(c + 1, kd0, vd0, kbase1, vbase1);
    }
#undef ATTN_CHUNK

    #pragma unroll
    for (int r = 0; r < 16; ++r) {
        const int qrow = qw + (r&3) + 8*(r>>2) + 4*hi;
        const size_t base = (((size_t)s*16 + bh)*SEQ + qrow)*64;
        Opart[base + l31]      = f2bf(o0[r]);
        Opart[base + 32 + l31] = f2bf(o1[r]);
    }
    if (hi == 0) {
        float2 ml; ml.x = mrun; ml.y = lrun;
        MLpart[((size_t)s*16 + bh)*SEQ + qw + l31] = ml;
    }
}

// ---------------------------------------------------------------------------
// Combine the NSPLIT KV-split parts (exact log-sum-exp merge, base-2 domain).
// ---------------------------------------------------------------------------
__global__ __launch_bounds__(256) void attn_combine_k(
    const ushort* __restrict__ Op, const float2* __restrict__ ML,
    ushort* __restrict__ attnb)
{
    const int row  = blockIdx.x * 4 + (threadIdx.x >> 6);  // bh*SEQ + q
    const int lane = threadIdx.x & 63;
    const int bh = row >> 11, q = row & 2047;
    const int b = bh >> 3, h = bh & 7;
    float2 ml[NSPLIT];
    float m = -1e30f;
    #pragma unroll
    for (int s = 0; s < NSPLIT; ++s) {
        ml[s] = ML[(size_t)s*16*SEQ + row];
        m = fmaxf(m, ml[s].x);
    }
    float l = 0.f, o = 0.f;
    #pragma unroll
    for (int s = 0; s < NSPLIT; ++s) {
        const float a = exp2f(ml[s].x - m);
        l += ml[s].y * a;
        o += bf2f(Op[((size_t)s*16*SEQ + row)*64 + lane]) * a;
    }
    attnb[((size_t)(b*SEQ + q))*DMODEL + h*DHEAD + lane] = f2bf(o / l);
}

// ---------------------------------------------------------------------------
// out = LayerNorm(X + A)*g + b over DMODEL=512, WAVE-PER-ROW (4 rows/block).
// ---------------------------------------------------------------------------
template<int XBF, int ABF>
__global__ __launch_bounds__(256) void add_ln_k(
    const void* __restrict__ X, const void* __restrict__ Aa,
    const float* __restrict__ gg, const float* __restrict__ bb,
    float* __restrict__ outf, ushort* __restrict__ outb)
{
    const int w = threadIdx.x >> 6, l = threadIdx.x & 63;
    const int r = blockIdx.x * 4 + w;
    const size_t base = (size_t)r * DMODEL + l * 8;

    float v[8];
    if (XBF) {
        bf16x8 u = *(const bf16x8*)((const ushort*)X + base);
        #pragma unroll
        for (int j = 0; j < 8; ++j) v[j] = bf2f((ushort)u[j]);
    } else {
        float4 f0 = *(const float4*)((const float*)X + base);
        float4 f1 = *(const float4*)((const float*)X + base + 4);
        v[0]=f0.x; v[1]=f0.y; v[2]=f0.z; v[3]=f0.w;
        v[4]=f1.x; v[5]=f1.y; v[6]=f1.z; v[7]=f1.w;
    }
    if (ABF) {
        bf16x8 u = *(const bf16x8*)((const ushort*)Aa + base);
        #pragma unroll
        for (int j = 0; j < 8; ++j) v[j] += bf2f((ushort)u[j]);
    } else {
        float4 f0 = *(const float4*)((const float*)Aa + base);
        float4 f1 = *(const float4*)((const float*)Aa + base + 4);
        v[0]+=f0.x; v[1]+=f0.y; v[2]+=f0.z; v[3]+=f0.w;
        v[4]+=f1.x; v[5]+=f1.y; v[6]+=f1.z; v[7]+=f1.w;
    }

    float s = 0.f, ss = 0.f;
    #pragma unroll
    for (int j = 0; j < 8; ++j) { s += v[j]; ss += v[j]*v[j]; }
    #pragma unroll
    for (int off = 32; off > 0; off >>= 1) {
        s  += __shfl_xor(s,  off);
        ss += __shfl_xor(ss, off);
    }
    const float mean = s * (1.0f / DMODEL);
    const float var  = ss * (1.0f / DMODEL) - mean * mean;
    const float rstd = rsqrtf(var + 1e-5f);

    const float4 g0 = *(const float4*)(gg + l*8);
    const float4 g1 = *(const float4*)(gg + l*8 + 4);
    const float4 b0 = *(const float4*)(bb + l*8);
    const float4 b1 = *(const float4*)(bb + l*8 + 4);
    float o[8];
    o[0] = (v[0]-mean)*rstd*g0.x + b0.x;
    o[1] = (v[1]-mean)*rstd*g0.y + b0.y;
    o[2] = (v[2]-mean)*rstd*g0.z + b0.z;
    o[3] = (v[3]-mean)*rstd*g0.w + b0.w;
    o[4] = (v[4]-mean)*rstd*g1.x + b1.x;
    o[5] = (v[5]-mean)*rstd*g1.y + b1.y;
    o[6] = (v[6]-mean)*rstd*g1.z + b1.z;
    o[7] = (v[7]-mean)*rstd*g1.w + b1.w;

    if (outf) {
        float4 f0, f1;
        f0.x=o[0]; f0.y=o[1]; f0.z=o[2]; f0.w=o[3];
        f1.x=o[4]; f1.y=o[5]; f1.z=o[6]; f1.w=o[7];
        *(float4*)(outf + base)     = f0;
        *(float4*)(outf + base + 4) = f1;
    }
    if (outb) {
        u32x4_bf16x8 cc;
        cc.u[0] = cvtpk_bf16(o[0], o[1]);
        cc.u[1] = cvtpk_bf16(o[2], o[3]);
        cc.u[2] = cvtpk_bf16(o[4], o[5]);
        cc.u[3] = cvtpk_bf16(o[6], o[7]);
        *(bf16x8*)(outb + base) = cc.v;
    }
}

// ---------------------------------------------------------------------------
extern "C" void kernel_launch(void* const* d_in, const int* in_sizes, int n_in,
                              void* d_out, int out_size, void* d_ws, size_t ws_size,
                              hipStream_t stream)
{
    const float* x      = (const float*)d_in[0];
    const void*  mask   = d_in[1];
    const float* W_qkv  = (const float*)d_in[2];
    const float* b_qkv  = (const float*)d_in[3];
    const float* W_proj = (const float*)d_in[4];
    const float* b_proj = (const float*)d_in[5];
    const float* ln1_g  = (const float*)d_in[6];
    const float* ln1_b  = (const float*)d_in[7];
    const float* W1     = (const float*)d_in[8];
    const float* b1     = (const float*)d_in[9];
    const float* W2     = (const float*)d_in[10];
    const float* b2     = (const float*)d_in[11];
    const float* ln2_g  = (const float*)d_in[12];
    const float* ln2_b  = (const float*)d_in[13];

    float* ws = (float*)d_ws;
    ushort* xb    = (ushort*)ws;
    ushort* Qb    = (ushort*)(ws + SZ/2);
    ushort* Kb    = (ushort*)(ws + SZ);
    ushort* Vtb   = (ushort*)(ws + SZ + SZ/2);   // [B,H,DHEAD,SEQ]
    ushort* attnb = (ushort*)(ws + 2*SZ);
    ushort* Opart = (ushort*)(ws + 2*SZ + SZ/2); // [4][16][SEQ][64] bf16
    float2* MLp   = (float2*)(ws + 4*SZ + SZ/2); // [4][16][SEQ]
    ushort* ap    = (ushort*)(ws + 2*SZ + SZ/2); // bf16, overlays Opart (dead)
    ushort* x1b   = (ushort*)(ws + 3*SZ);        // bf16
    ushort* mbuf  = (ushort*)(ws + 3*SZ + SZ/2); // bf16
    ushort* hb    = (ushort*)ws;
    ushort* WqkvT = (ushort*)(ws + 5*SZ);                    // 512*1536
    ushort* WprojT= (ushort*)(ws + 5*SZ + 393216);           // 512*512
    ushort* W1T   = (ushort*)(ws + 5*SZ + 524288);           // 2048*512
    ushort* W2T   = (ushort*)(ws + 5*SZ + 1048576);          // 512*2048
    unsigned long long* bits = (unsigned long long*)(ws + 5*SZ + 1572864);
    int*    flag  = (int*)(ws + 5*SZ + 1572864 + 262144);

    float* out = (float*)d_out;

    hipMemsetAsync(flag, 0, 4, stream);
    detect_mask_k<<<64, 256, 0, stream>>>((const uint4*)mask, flag);
    prep_all_k<<<2816 + 32768, 256, 0, stream>>>(
        x, xb, W_qkv, W_proj, W1, W2, WqkvT, WprojT, W1T, W2T,
        mask, flag, bits);

    // QKV: [4096,512]@[512,1536] -> bf16 Q/K (row) + V (transposed)
    mgemm_k<3,64,128><<<dim3(12, 64), 256, 0, stream>>>(xb, WqkvT, b_qkv,
        nullptr, Qb, Kb, Vtb, ROWS, 3*DMODEL, DMODEL);
    // attention partials (4-way KV split) -> combine -> attnb bf16
    attn_mfma_k<<<dim3(256, NSPLIT), 256, 0, stream>>>(
        Qb, Kb, Vtb, bits, Opart, MLp);
    attn_combine_k<<<BATCH*NH*SEQ/4, 256, 0, stream>>>(Opart, MLp, attnb);
    // proj: [4096,512]@[512,512] -> ap bf16
    mgemm_k<4,64,64><<<dim3(8, 64), 256, 0, stream>>>(attnb, WprojT, b_proj,
        ap, nullptr, nullptr, nullptr, ROWS, DMODEL, DMODEL);
    // x1b = LN(xb + ap)
    add_ln_k<1,1><<<ROWS/4, 256, 0, stream>>>(xb, ap, ln1_g, ln1_b, nullptr, x1b);
    // MLP1: relu([4096,512]@[512,2048]) -> bf16 hb
    mgemm_k<1,64,128><<<dim3(16, 64), 256, 0, stream>>>(x1b, W1T, b1,
        hb, nullptr, nullptr, nullptr, ROWS, 2048, DMODEL);
    // MLP2: relu([4096,2048]@[2048,512]) -> bf16 mbuf
    mgemm_k<1,64,64><<<dim3(8, 64), 256, 0, stream>>>(hb, W2T, b2,
        mbuf, nullptr, nullptr, nullptr, ROWS, DMODEL, 2048);
    // out = LN(x1b + mbuf) -> f32 d_out
    add_ln_k<1,1><<<ROWS/4, 256, 0, stream>>>(x1b, mbuf, ln2_g, ln2_b, out, nullptr);
}

// Round 15
// 144.822 us; speedup vs baseline: 1.0905x; 1.0286x over previous
//
#include <hip/hip_runtime.h>
#include <math.h>

// Problem constants
constexpr int BATCH  = 2;
constexpr int SEQ    = 2048;
constexpr int DMODEL = 512;
constexpr int NH     = 8;
constexpr int DHEAD  = 64;
constexpr int ROWS   = BATCH * SEQ;           // 4096
constexpr size_t SZ  = (size_t)ROWS * DMODEL; // elems of one [4096][512] f32 buffer
constexpr int NSPLIT = 4;                     // attention KV-split ways

typedef __attribute__((ext_vector_type(8)))  short bf16x8;
typedef __attribute__((ext_vector_type(4)))  float f32x4;
typedef __attribute__((ext_vector_type(16))) float f32x16;

__device__ __forceinline__ ushort f2bf(float f) {
    unsigned u = __float_as_uint(f);
    unsigned r = (u + 0x7FFFu + ((u >> 16) & 1u)) >> 16;
    return (ushort)r;
}
__device__ __forceinline__ float bf2f(ushort u) {
    return __uint_as_float((unsigned)u << 16);
}

// pack 2 f32 -> 2 bf16 (RNE) in one instruction
__device__ __forceinline__ unsigned cvtpk_bf16(float lo, float hi) {
    unsigned r;
    asm("v_cvt_pk_bf16_f32 %0, %1, %2" : "=v"(r) : "v"(lo), "v"(hi));
    return r;
}

__device__ __forceinline__ void gload_lds16(const void* g, void* l) {
    __builtin_amdgcn_global_load_lds(
        (const __attribute__((address_space(1))) void*)g,
        (__attribute__((address_space(3))) void*)l, 16, 0, 0);
}

union u32x4_bf16x8 { unsigned u[4]; bf16x8 v; };

// ---------------------------------------------------------------------------
// Mask-encoding detector, parallel. flag MUST be zeroed before launch.
// ---------------------------------------------------------------------------
__global__ __launch_bounds__(256) void detect_mask_k(
    const uint4* __restrict__ m, int* __restrict__ flag)
{
    const int i = blockIdx.x * 256 + threadIdx.x;
    const uint4 v = m[i];
    unsigned b0 = 0, b1 = 0;
    #pragma unroll
    for (int c = 0; c < 4; ++c) {
        const unsigned u = (&v.x)[c];
        b0 |= (u > 1u) ? 1u : 0u;
        b1 |= (u != 0u && u != 0x3F800000u) ? 1u : 0u;
    }
    const int lane = threadIdx.x & 63;
    if (__any(b0) && lane == 0) atomicOr(flag, 1);
    if (__any(b1) && lane == 0) atomicOr(flag, 2);
}

// ---------------------------------------------------------------------------
// Fused prep: [0,2048) x f32->bf16 conv | [2048,2816) weight transpose+conv
//             [2816, 2816+2048) mask bitmask compaction (64 words per block:
//             each wave loops 16 ballot rounds -- was 32768 tiny blocks)
// ---------------------------------------------------------------------------
__global__ __launch_bounds__(256) void prep_all_k(
    const float* __restrict__ x, ushort* __restrict__ xb,
    const float* __restrict__ Wq, const float* __restrict__ Wp,
    const float* __restrict__ W1w, const float* __restrict__ W2w,
    ushort* __restrict__ WqT, ushort* __restrict__ WpT,
    ushort* __restrict__ W1T, ushort* __restrict__ W2T,
    const void* __restrict__ maskp, const int* __restrict__ flagp,
    unsigned long long* __restrict__ bits)
{
    __shared__ ushort T[64][65];
    const int bid = blockIdx.x;
    const int t = threadIdx.x;

    if (bid < 2048) {           // x f32 -> bf16
        const size_t i = ((size_t)bid * 256 + t) * 4;
        float4 v = *(const float4*)(x + i);
        ushort4 o;
        o.x = f2bf(v.x); o.y = f2bf(v.y); o.z = f2bf(v.z); o.w = f2bf(v.w);
        *(ushort4*)(xb + i) = o;
        return;
    }
    if (bid >= 2816) {          // mask -> bitmask, 64 words/block
        const int lane = t & 63;
        const int w0 = (bid - 2816) * 64 + (t >> 6) * 16;
        const int f = *flagp;
        #pragma unroll 4
        for (int r = 0; r < 16; ++r) {
            const int w = w0 + r;
            const size_t idx = ((size_t)w << 6) + lane;
            bool mv;
            if (!(f & 1))      mv = ((const int*)maskp)[idx] != 0;
            else if (!(f & 2)) mv = ((const float*)maskp)[idx] != 0.f;
            else               mv = ((const unsigned char*)maskp)[idx] != 0;
            unsigned long long bal = __ballot(mv);
            if (lane == 0) bits[w] = bal;
        }
        return;
    }
    // weight transpose+convert, 64x64 tiles
    const int wb = bid - 2048;
    const float* W; ushort* Wt; int K, N, tix, tiy;
    if (wb < 192)      { W = Wq;  Wt = WqT; K = 512;  N = 1536; tix = wb % 24;        tiy = wb / 24; }
    else if (wb < 256) { W = Wp;  Wt = WpT; K = 512;  N = 512;  tix = (wb-192) % 8;   tiy = (wb-192) / 8; }
    else if (wb < 512) { W = W1w; Wt = W1T; K = 512;  N = 2048; tix = (wb-256) % 32;  tiy = (wb-256) / 32; }
    else               { W = W2w; Wt = W2T; K = 2048; N = 512;  tix = (wb-512) % 8;   tiy = (wb-512) / 8; }
    const int k0 = tiy * 64, n0 = tix * 64;
    const int r = t >> 4, c4 = (t & 15) * 4;
    #pragma unroll
    for (int it = 0; it < 4; ++it) {
        const int row = it*16 + r;
        float4 v = *(const float4*)&W[(size_t)(k0 + row) * N + n0 + c4];
        T[c4+0][row] = f2bf(v.x);
        T[c4+1][row] = f2bf(v.y);
        T[c4+2][row] = f2bf(v.z);
        T[c4+3][row] = f2bf(v.w);
    }
    __syncthreads();
    #pragma unroll
    for (int it = 0; it < 4; ++it) {
        const int row = it*16 + r;
        ushort4 o;
        o.x = T[row][c4+0]; o.y = T[row][c4+1];
        o.z = T[row][c4+2]; o.w = T[row][c4+3];
        *(ushort4*)&Wt[(size_t)(n0 + row) * K + k0 + c4] = o;
    }
}

// ---------------------------------------------------------------------------
// bf16 MFMA GEMM (m97 structure, single-buffered) + T1 XCD-aware bijective
// block swizzle (round-14 proven config).
// EPI: 1 = relu(bias) -> bf16 | 3 = QKV scatter (V transposed) | 4 = bias -> bf16
// ---------------------------------------------------------------------------
template<int EPI, int BM, int BN>
__global__ __launch_bounds__(256) void mgemm_k(
    const ushort* __restrict__ A,   // [M][K] bf16
    const ushort* __restrict__ Wt,  // [N][K] bf16
    const float* __restrict__ bias, // [N] f32
    ushort* __restrict__ Cb,
    ushort* __restrict__ Qo, ushort* __restrict__ Ko, ushort* __restrict__ Vo,
    int M, int N, int K)
{
    constexpr int WM  = BM / 2, WN = BN / 2;
    constexpr int MF  = WM / 16, NF = WN / 16;
    constexpr int APW = BM / 32;
    constexpr int BPW = BN / 32;

    __shared__ ushort As[BM * 64];
    __shared__ ushort Bs[BN * 64];

    const int tid  = threadIdx.x;
    const int wid  = tid >> 6, lane = tid & 63;
    const int lq   = lane & 15, lg = lane >> 4;
    const int wr   = wid >> 1,  wc = wid & 1;

    // XCD-aware bijective swizzle (nwg % 8 == 0).
    const int gx   = gridDim.x;
    const int nwg  = gx * gridDim.y;
    const int lin  = blockIdx.y * gx + blockIdx.x;
    const int cpx  = nwg >> 3;
    const int pos  = (lin & 7) * cpx + (lin >> 3);
    const int bm   = (pos / gx) * BM, bn = (pos % gx) * BN;

    const int srow0 = lane >> 3;
    const int sch   = lane & 7;

    f32x4 acc[MF][NF] = {};

    for (int k0 = 0; k0 < K; k0 += 64) {
        __syncthreads();
        #pragma unroll
        for (int i = 0; i < APW; ++i) {
            const int seg = wid * APW + i;
            const int row = seg * 8 + srow0;
            const int c16 = sch ^ (row & 7);
            gload_lds16(A + (size_t)(bm + row) * K + k0 + c16 * 8, As + seg * 512);
        }
        #pragma unroll
        for (int i = 0; i < BPW; ++i) {
            const int seg = wid * BPW + i;
            const int row = seg * 8 + srow0;
            const int c16 = sch ^ (row & 7);
            gload_lds16(Wt + (size_t)(bn + row) * K + k0 + c16 * 8, Bs + seg * 512);
        }
        __syncthreads();

        #pragma unroll
        for (int ks = 0; ks < 2; ++ks) {
            bf16x8 af[MF], bfr[NF];
            #pragma unroll
            for (int m = 0; m < MF; ++m) {
                const int row = wr*WM + m*16 + lq;
                const int c16 = (ks*4 + lg) ^ (row & 7);
                af[m] = *(const bf16x8*)&As[row * 64 + c16 * 8];
            }
            #pragma unroll
            for (int n = 0; n < NF; ++n) {
                const int row = wc*WN + n*16 + lq;
                const int c16 = (ks*4 + lg) ^ (row & 7);
                bfr[n] = *(const bf16x8*)&Bs[row * 64 + c16 * 8];
            }
            #pragma unroll
            for (int m = 0; m < MF; ++m)
                #pragma unroll
                for (int n = 0; n < NF; ++n)
                    acc[m][n] = __builtin_amdgcn_mfma_f32_16x16x32_bf16(
                        af[m], bfr[n], acc[m][n], 0, 0, 0);
        }
    }

    #pragma unroll
    for (int m = 0; m < MF; ++m) {
        const int row0 = bm + wr*WM + m*16 + lg*4;
        #pragma unroll
        for (int n = 0; n < NF; ++n) {
            const int col = bn + wc*WN + n*16 + lq;
            const float bv = bias[col];
            float v[4];
            #pragma unroll
            for (int r = 0; r < 4; ++r) {
                v[r] = acc[m][n][r] + bv;
                if (EPI == 1) v[r] = fmaxf(v[r], 0.f);
            }
            if (EPI == 3) {
                const int part = col >> 9, hc = col & 511;
                const int hh = hc >> 6, d0 = hc & 63;
                const int bidx = row0 >> 11, nrow0 = row0 & 2047;
                if (part == 2) {
                    ushort4 pv;
                    pv.x = f2bf(v[0]); pv.y = f2bf(v[1]);
                    pv.z = f2bf(v[2]); pv.w = f2bf(v[3]);
                    *(ushort4*)(Vo + (((size_t)bidx*NH + hh)*DHEAD + d0)*SEQ + nrow0) = pv;
                } else {
                    ushort* dst = (part == 0) ? Qo : Ko;
                    #pragma unroll
                    for (int r = 0; r < 4; ++r)
                        dst[((((size_t)bidx*NH + hh)*SEQ + nrow0 + r) << 6) + d0] = f2bf(v[r]);
                }
            } else {
                #pragma unroll
                for (int r = 0; r < 4; ++r)
                    Cb[(size_t)(row0 + r) * N + col] = f2bf(v[r]);
            }
        }
    }
}

// ---------------------------------------------------------------------------
// bf16 MFMA flash attention, v7 (round-10/14 proven config, (256,4))
// + max3-friendly softmax max trees (v_max3_f32 fusion, exact same result).
// Grid: (256, NSPLIT); x = tile*16 + bh so linear%8 = bh%8 (XCD locality).
// ---------------------------------------------------------------------------
__global__ __launch_bounds__(256, 4) void attn_mfma_k(
    const ushort* __restrict__ Qb, const ushort* __restrict__ Kb,
    const ushort* __restrict__ Vtb, const unsigned long long* __restrict__ mbits,
    ushort* __restrict__ Opart, float2* __restrict__ MLpart)
{
    __shared__ ushort Klds[2][64 * 64];   // [key][d], XOR-swizzled 16B chunks
    __shared__ ushort Vlds[2][64 * 64];   // [d][key], XOR-swizzled

    const int tid  = threadIdx.x;
    const int wid  = tid >> 6;
    const int lane = tid & 63;
    const int l31  = lane & 31;
    const int hi   = lane >> 5;

    const int bh   = blockIdx.x & 15;
    const int tile = blockIdx.x >> 4;     // 0..15 (SEQ/128 q-tiles)
    const int b    = bh >> 3;
    const int qw   = tile * 128 + wid * 32;
    const int s    = blockIdx.y;
    const int c0   = s * 8, c1 = c0 + 8;

    const float k2 = 0.125f * 1.44269504f;   // 1/sqrt(dh) * log2(e)

    // Q fragments (B-operand of 32x32x16), pre-scaled by k2.
    bf16x8 qf[4];
    {
        const ushort* Qg = Qb + ((size_t)bh * SEQ + qw + l31) * DHEAD;
        #pragma unroll
        for (int kd = 0; kd < 4; ++kd) {
            bf16x8 raw = *(const bf16x8*)(Qg + kd*16 + hi*8);
            u32x4_bf16x8 cc;
            #pragma unroll
            for (int p2 = 0; p2 < 4; ++p2) {
                const float a = bf2f((ushort)raw[2*p2])   * k2;
                const float c = bf2f((ushort)raw[2*p2+1]) * k2;
                cc.u[p2] = cvtpk_bf16(a, c);
            }
            qf[kd] = cc.v;
        }
    }

    const int srow0 = lane >> 3;
    const int sch   = lane & 7;
    const int gc8   = (sch ^ srow0) * 8;      // inverse-swizzled global col

    const ushort* kgb  = Kb  + (size_t)bh * SEQ * DHEAD
                             + (size_t)(wid*16 + srow0) * DHEAD + gc8;
    const ushort* vgb0 = Vtb + (size_t)bh * DHEAD * SEQ
                             + (size_t)(wid*16 + srow0) * SEQ + gc8;
    const ushort* vgb1 = vgb0 + 8 * SEQ;

    ushort* kd0 = &Klds[0][(wid*2)*512];
    ushort* kd1 = &Klds[1][(wid*2)*512];
    ushort* vd0 = &Vlds[0][(wid*2)*512];
    ushort* vd1 = &Vlds[1][(wid*2)*512];

    int kro0[4], kro1[4], vro[4][2];
    #pragma unroll
    for (int kd = 0; kd < 4; ++kd) {
        kro0[kd] = ( (l31)      * 64 + (((kd*2+hi) ^ (lane&7)) * 8) ) * 2;
        kro1[kd] = ( (32 + l31) * 64 + (((kd*2+hi) ^ (lane&7)) * 8) ) * 2;
    }
    #pragma unroll
    for (int ks = 0; ks < 4; ++ks)
        #pragma unroll
        for (int dt = 0; dt < 2; ++dt)
            vro[ks][dt] = ( (dt*32 + l31) * 64 + (((ks*2+hi) ^ (lane&7)) * 8) ) * 2;

    const char* kbase0 = (const char*)&Klds[0][0];
    const char* kbase1 = (const char*)&Klds[1][0];
    const char* vbase0 = (const char*)&Vlds[0][0];
    const char* vbase1 = (const char*)&Vlds[1][0];

    const unsigned long long* mrow = mbits + ((size_t)b * SEQ + qw + l31) * (SEQ / 64);

    f32x16 o0 = {}, o1 = {};
    float mrun = -1e30f, lrun = 0.f;

    {
        const ushort* kp0 = kgb  + (size_t)c0 * 4096;
        const ushort* vq0 = vgb0 + c0 * 64;
        const ushort* vq1 = vgb1 + c0 * 64;
        gload_lds16(kp0,       kd0);
        gload_lds16(kp0 + 512, kd0 + 512);
        gload_lds16(vq0, vd0);
        gload_lds16(vq1, vd0 + 512);
    }
    const ushort* kp  = kgb  + (size_t)(c0 + 1) * 4096;
    const ushort* vp0 = vgb0 + (c0 + 1) * 64;
    const ushort* vp1 = vgb1 + (c0 + 1) * 64;
    unsigned long long mw_cur = mrow[c0];
    __syncthreads();

#define M3(a,b,c) fmaxf(fmaxf((a),(b)),(c))
#define ATTN_CHUNK(CC, KD, VD, KBASE, VBASE)                                   \
    {                                                                          \
        unsigned long long mw_nxt = 0;                                         \
        if ((CC) + 1 < c1) {                                                   \
            mw_nxt = mrow[(CC) + 1];                                           \
            gload_lds16(kp,       (KD));                                       \
            gload_lds16(kp + 512, (KD) + 512);                                 \
            gload_lds16(vp0, (VD));                                            \
            gload_lds16(vp1, (VD) + 512);                                      \
            kp += 4096; vp0 += 64; vp1 += 64;                                  \
        }                                                                      \
        f32x16 st0 = {}, st1 = {};                                             \
        __builtin_amdgcn_s_setprio(1);                                         \
        _Pragma("unroll")                                                      \
        for (int kd = 0; kd < 4; ++kd) {                                       \
            bf16x8 kf0 = *(const bf16x8*)((KBASE) + kro0[kd]);                 \
            bf16x8 kf1 = *(const bf16x8*)((KBASE) + kro1[kd]);                 \
            st0 = __builtin_amdgcn_mfma_f32_32x32x16_bf16(kf0, qf[kd], st0, 0, 0, 0); \
            st1 = __builtin_amdgcn_mfma_f32_32x32x16_bf16(kf1, qf[kd], st1, 0, 0, 0); \
        }                                                                      \
        __builtin_amdgcn_s_setprio(0);                                         \
        const unsigned long long mws = mw_cur >> (hi * 4);                     \
        const unsigned mlo = (unsigned)mws, mhi2 = (unsigned)(mws >> 32);      \
        _Pragma("unroll")                                                      \
        for (int r = 0; r < 16; ++r) {                                         \
            const int pos = (r & 3) + 8 * (r >> 2);                            \
            st0[r] = ((mlo  >> pos) & 1u) ? st0[r] : -1e9f;                    \
            st1[r] = ((mhi2 >> pos) & 1u) ? st1[r] : -1e9f;                    \
        }                                                                      \
        const float a0 = M3(st0[0],st0[1],st0[2]);                             \
        const float a1 = M3(st0[3],st0[4],st0[5]);                             \
        const float a2 = M3(st0[6],st0[7],st0[8]);                             \
        const float a3 = M3(st0[9],st0[10],st0[11]);                           \
        const float a4 = M3(st0[12],st0[13],st0[14]);                          \
        const float cm0 = fmaxf(M3(a0,a1,a2), M3(a3,a4,st0[15]));              \
        const float b0_ = M3(st1[0],st1[1],st1[2]);                            \
        const float b1_ = M3(st1[3],st1[4],st1[5]);                            \
        const float b2_ = M3(st1[6],st1[7],st1[8]);                            \
        const float b3_ = M3(st1[9],st1[10],st1[11]);                          \
        const float b4_ = M3(st1[12],st1[13],st1[14]);                         \
        const float cm1 = fmaxf(M3(b0_,b1_,b2_), M3(b3_,b4_,st1[15]));         \
        float cmax = fmaxf(cm0, cm1);                                          \
        cmax = fmaxf(cmax, __shfl_xor(cmax, 32));                              \
        if (!__all(cmax <= mrun + 8.0f)) {                                     \
            const float mnew  = fmaxf(mrun, cmax);                             \
            const float scale = exp2f(mrun - mnew);                            \
            _Pragma("unroll")                                                  \
            for (int r = 0; r < 16; ++r) {                                     \
                const float sc = __shfl(scale, (r&3) + 8*(r>>2) + 4*hi);       \
                o0[r] *= sc; o1[r] *= sc;                                      \
            }                                                                  \
            lrun *= scale;                                                     \
            mrun = mnew;                                                       \
        }                                                                      \
        float lsum = 0.f;                                                      \
        _Pragma("unroll")                                                      \
        for (int r = 0; r < 16; ++r) {                                         \
            st0[r] = exp2f(st0[r] - mrun);                                     \
            st1[r] = exp2f(st1[r] - mrun);                                     \
            lsum += st0[r] + st1[r];                                           \
        }                                                                      \
        lsum += __shfl_xor(lsum, 32);                                          \
        lrun += lsum;                                                          \
        unsigned w0[8], w1[8];                                                 \
        _Pragma("unroll")                                                      \
        for (int g = 0; g < 4; ++g) {                                          \
            w0[2*g]   = cvtpk_bf16(st0[4*g+0], st0[4*g+1]);                    \
            w0[2*g+1] = cvtpk_bf16(st0[4*g+2], st0[4*g+3]);                    \
            w1[2*g]   = cvtpk_bf16(st1[4*g+0], st1[4*g+1]);                    \
            w1[2*g+1] = cvtpk_bf16(st1[4*g+2], st1[4*g+3]);                    \
        }                                                                      \
        unsigned rcv0[4], rcv1[4];                                             \
        _Pragma("unroll")                                                      \
        for (int i = 0; i < 4; ++i) {                                          \
            const int i2 = i >> 1, wi = i & 1;                                 \
            const unsigned s0 = hi ? w0[4*i2+wi] : w0[4*i2+2+wi];              \
            const unsigned s1 = hi ? w1[4*i2+wi] : w1[4*i2+2+wi];              \
            rcv0[i] = (unsigned)__shfl_xor((int)s0, 32);                       \
            rcv1[i] = (unsigned)__shfl_xor((int)s1, 32);                       \
        }                                                                      \
        __builtin_amdgcn_s_setprio(1);                                         \
        _Pragma("unroll")                                                      \
        for (int ks = 0; ks < 4; ++ks) {                                       \
            const int i2 = ks & 1;                                             \
            u32x4_bf16x8 fw;                                                   \
            if (ks < 2) {                                                      \
                fw.u[0] = hi ? rcv0[2*i2+0] : w0[4*i2+0];                      \
                fw.u[1] = hi ? rcv0[2*i2+1] : w0[4*i2+1];                      \
                fw.u[2] = hi ? w0[4*i2+2]   : rcv0[2*i2+0];                    \
                fw.u[3] = hi ? w0[4*i2+3]   : rcv0[2*i2+1];                    \
            } else {                                                           \
                fw.u[0] = hi ? rcv1[2*i2+0] : w1[4*i2+0];                      \
                fw.u[1] = hi ? rcv1[2*i2+1] : w1[4*i2+1];                      \
                fw.u[2] = hi ? w1[4*i2+2]   : rcv1[2*i2+0];                    \
                fw.u[3] = hi ? w1[4*i2+3]   : rcv1[2*i2+1];                    \
            }                                                                  \
            bf16x8 vf0 = *(const bf16x8*)((VBASE) + vro[ks][0]);               \
            bf16x8 vf1 = *(const bf16x8*)((VBASE) + vro[ks][1]);               \
            o0 = __builtin_amdgcn_mfma_f32_32x32x16_bf16(fw.v, vf0, o0, 0, 0, 0); \
            o1 = __builtin_amdgcn_mfma_f32_32x32x16_bf16(fw.v, vf1, o1, 0, 0, 0); \
        }                                                                      \
        __builtin_amdgcn_s_setprio(0);                                         \
        __syncthreads();                                                       \
        mw_cur = mw_nxt;                                                       \
    }

    for (int c = c0; c < c1; c += 2) {
        ATTN_CHUNK(c,     kd1, vd1, kbase0, vbase0);
        ATTN_CHUNK(c + 1, kd0, vd0, kbase1, vbase1);
    }
#undef ATTN_CHUNK
#undef M3

    #pragma unroll
    for (int r = 0; r < 16; ++r) {
        const int qrow = qw + (r&3) + 8*(r>>2) + 4*hi;
        const size_t base = (((size_t)s*16 + bh)*SEQ + qrow)*64;
        Opart[base + l31]      = f2bf(o0[r]);
        Opart[base + 32 + l31] = f2bf(o1[r]);
    }
    if (hi == 0) {
        float2 ml; ml.x = mrun; ml.y = lrun;
        MLpart[((size_t)s*16 + bh)*SEQ + qw + l31] = ml;
    }
}

// ---------------------------------------------------------------------------
// Combine the NSPLIT KV-split parts (exact log-sum-exp merge, base-2 domain).
// ---------------------------------------------------------------------------
__global__ __launch_bounds__(256) void attn_combine_k(
    const ushort* __restrict__ Op, const float2* __restrict__ ML,
    ushort* __restrict__ attnb)
{
    const int row  = blockIdx.x * 4 + (threadIdx.x >> 6);  // bh*SEQ + q
    const int lane = threadIdx.x & 63;
    const int bh = row >> 11, q = row & 2047;
    const int b = bh >> 3, h = bh & 7;
    float2 ml[NSPLIT];
    float m = -1e30f;
    #pragma unroll
    for (int s = 0; s < NSPLIT; ++s) {
        ml[s] = ML[(size_t)s*16*SEQ + row];
        m = fmaxf(m, ml[s].x);
    }
    float l = 0.f, o = 0.f;
    #pragma unroll
    for (int s = 0; s < NSPLIT; ++s) {
        const float a = exp2f(ml[s].x - m);
        l += ml[s].y * a;
        o += bf2f(Op[((size_t)s*16*SEQ + row)*64 + lane]) * a;
    }
    attnb[((size_t)(b*SEQ + q))*DMODEL + h*DHEAD + lane] = f2bf(o / l);
}

// ---------------------------------------------------------------------------
// out = LayerNorm(X + A)*g + b over DMODEL=512, WAVE-PER-ROW (4 rows/block).
// ---------------------------------------------------------------------------
template<int XBF, int ABF>
__global__ __launch_bounds__(256) void add_ln_k(
    const void* __restrict__ X, const void* __restrict__ Aa,
    const float* __restrict__ gg, const float* __restrict__ bb,
    float* __restrict__ outf, ushort* __restrict__ outb)
{
    const int w = threadIdx.x >> 6, l = threadIdx.x & 63;
    const int r = blockIdx.x * 4 + w;
    const size_t base = (size_t)r * DMODEL + l * 8;

    float v[8];
    if (XBF) {
        bf16x8 u = *(const bf16x8*)((const ushort*)X + base);
        #pragma unroll
        for (int j = 0; j < 8; ++j) v[j] = bf2f((ushort)u[j]);
    } else {
        float4 f0 = *(const float4*)((const float*)X + base);
        float4 f1 = *(const float4*)((const float*)X + base + 4);
        v[0]=f0.x; v[1]=f0.y; v[2]=f0.z; v[3]=f0.w;
        v[4]=f1.x; v[5]=f1.y; v[6]=f1.z; v[7]=f1.w;
    }
    if (ABF) {
        bf16x8 u = *(const bf16x8*)((const ushort*)Aa + base);
        #pragma unroll
        for (int j = 0; j < 8; ++j) v[j] += bf2f((ushort)u[j]);
    } else {
        float4 f0 = *(const float4*)((const float*)Aa + base);
        float4 f1 = *(const float4*)((const float*)Aa + base + 4);
        v[0]+=f0.x; v[1]+=f0.y; v[2]+=f0.z; v[3]+=f0.w;
        v[4]+=f1.x; v[5]+=f1.y; v[6]+=f1.z; v[7]+=f1.w;
    }

    float s = 0.f, ss = 0.f;
    #pragma unroll
    for (int j = 0; j < 8; ++j) { s += v[j]; ss += v[j]*v[j]; }
    #pragma unroll
    for (int off = 32; off > 0; off >>= 1) {
        s  += __shfl_xor(s,  off);
        ss += __shfl_xor(ss, off);
    }
    const float mean = s * (1.0f / DMODEL);
    const float var  = ss * (1.0f / DMODEL) - mean * mean;
    const float rstd = rsqrtf(var + 1e-5f);

    const float4 g0 = *(const float4*)(gg + l*8);
    const float4 g1 = *(const float4*)(gg + l*8 + 4);
    const float4 b0 = *(const float4*)(bb + l*8);
    const float4 b1 = *(const float4*)(bb + l*8 + 4);
    float o[8];
    o[0] = (v[0]-mean)*rstd*g0.x + b0.x;
    o[1] = (v[1]-mean)*rstd*g0.y + b0.y;
    o[2] = (v[2]-mean)*rstd*g0.z + b0.z;
    o[3] = (v[3]-mean)*rstd*g0.w + b0.w;
    o[4] = (v[4]-mean)*rstd*g1.x + b1.x;
    o[5] = (v[5]-mean)*rstd*g1.y + b1.y;
    o[6] = (v[6]-mean)*rstd*g1.z + b1.z;
    o[7] = (v[7]-mean)*rstd*g1.w + b1.w;

    if (outf) {
        float4 f0, f1;
        f0.x=o[0]; f0.y=o[1]; f0.z=o[2]; f0.w=o[3];
        f1.x=o[4]; f1.y=o[5]; f1.z=o[6]; f1.w=o[7];
        *(float4*)(outf + base)     = f0;
        *(float4*)(outf + base + 4) = f1;
    }
    if (outb) {
        u32x4_bf16x8 cc;
        cc.u[0] = cvtpk_bf16(o[0], o[1]);
        cc.u[1] = cvtpk_bf16(o[2], o[3]);
        cc.u[2] = cvtpk_bf16(o[4], o[5]);
        cc.u[3] = cvtpk_bf16(o[6], o[7]);
        *(bf16x8*)(outb + base) = cc.v;
    }
}

// ---------------------------------------------------------------------------
extern "C" void kernel_launch(void* const* d_in, const int* in_sizes, int n_in,
                              void* d_out, int out_size, void* d_ws, size_t ws_size,
                              hipStream_t stream)
{
    const float* x      = (const float*)d_in[0];
    const void*  mask   = d_in[1];
    const float* W_qkv  = (const float*)d_in[2];
    const float* b_qkv  = (const float*)d_in[3];
    const float* W_proj = (const float*)d_in[4];
    const float* b_proj = (const float*)d_in[5];
    const float* ln1_g  = (const float*)d_in[6];
    const float* ln1_b  = (const float*)d_in[7];
    const float* W1     = (const float*)d_in[8];
    const float* b1     = (const float*)d_in[9];
    const float* W2     = (const float*)d_in[10];
    const float* b2     = (const float*)d_in[11];
    const float* ln2_g  = (const float*)d_in[12];
    const float* ln2_b  = (const float*)d_in[13];

    float* ws = (float*)d_ws;
    ushort* xb    = (ushort*)ws;
    ushort* Qb    = (ushort*)(ws + SZ/2);
    ushort* Kb    = (ushort*)(ws + SZ);
    ushort* Vtb   = (ushort*)(ws + SZ + SZ/2);   // [B,H,DHEAD,SEQ]
    ushort* attnb = (ushort*)(ws + 2*SZ);
    ushort* Opart = (ushort*)(ws + 2*SZ + SZ/2); // [4][16][SEQ][64] bf16
    float2* MLp   = (float2*)(ws + 4*SZ + SZ/2); // [4][16][SEQ]
    ushort* ap    = (ushort*)(ws + 2*SZ + SZ/2); // bf16, overlays Opart (dead)
    ushort* x1b   = (ushort*)(ws + 3*SZ);        // bf16
    ushort* mbuf  = (ushort*)(ws + 3*SZ + SZ/2); // bf16
    ushort* hb    = (ushort*)ws;
    ushort* WqkvT = (ushort*)(ws + 5*SZ);                    // 512*1536
    ushort* WprojT= (ushort*)(ws + 5*SZ + 393216);           // 512*512
    ushort* W1T   = (ushort*)(ws + 5*SZ + 524288);           // 2048*512
    ushort* W2T   = (ushort*)(ws + 5*SZ + 1048576);          // 512*2048
    unsigned long long* bits = (unsigned long long*)(ws + 5*SZ + 1572864);
    int*    flag  = (int*)(ws + 5*SZ + 1572864 + 262144);

    float* out = (float*)d_out;

    hipMemsetAsync(flag, 0, 4, stream);
    detect_mask_k<<<64, 256, 0, stream>>>((const uint4*)mask, flag);
    prep_all_k<<<2816 + 2048, 256, 0, stream>>>(
        x, xb, W_qkv, W_proj, W1, W2, WqkvT, WprojT, W1T, W2T,
        mask, flag, bits);

    // QKV: [4096,512]@[512,1536] -> bf16 Q/K (row) + V (transposed)
    mgemm_k<3,64,128><<<dim3(12, 64), 256, 0, stream>>>(xb, WqkvT, b_qkv,
        nullptr, Qb, Kb, Vtb, ROWS, 3*DMODEL, DMODEL);
    // attention partials (4-way KV split) -> combine -> attnb bf16
    attn_mfma_k<<<dim3(256, NSPLIT), 256, 0, stream>>>(
        Qb, Kb, Vtb, bits, Opart, MLp);
    attn_combine_k<<<BATCH*NH*SEQ/4, 256, 0, stream>>>(Opart, MLp, attnb);
    // proj: [4096,512]@[512,512] -> ap bf16
    mgemm_k<4,64,64><<<dim3(8, 64), 256, 0, stream>>>(attnb, WprojT, b_proj,
        ap, nullptr, nullptr, nullptr, ROWS, DMODEL, DMODEL);
    // x1b = LN(xb + ap)
    add_ln_k<1,1><<<ROWS/4, 256, 0, stream>>>(xb, ap, ln1_g, ln1_b, nullptr, x1b);
    // MLP1: relu([4096,512]@[512,2048]) -> bf16 hb
    mgemm_k<1,64,128><<<dim3(16, 64), 256, 0, stream>>>(x1b, W1T, b1,
        hb, nullptr, nullptr, nullptr, ROWS, 2048, DMODEL);
    // MLP2: relu([4096,2048]@[2048,512]) -> bf16 mbuf
    mgemm_k<1,64,64><<<dim3(8, 64), 256, 0, stream>>>(hb, W2T, b2,
        mbuf, nullptr, nullptr, nullptr, ROWS, DMODEL, 2048);
    // out = LN(x1b + mbuf) -> f32 d_out
    add_ln_k<1,1><<<ROWS/4, 256, 0, stream>>>(x1b, mbuf, ln2_g, ln2_b, out, nullptr);
}